// Round 5
// baseline (1684.434 us; speedup 1.0000x reference)
//
#include <hip/hip_runtime.h>
#include <math.h>

namespace {
constexpr int BN = 64;
constexpr int HW = 1024;
constexpr int NS = BN*8*HW;      // 524288

constexpr float C2f = 0.2f, C3f = 0.3f, C4f = 0.8f, C5f = (float)(8.0/9.0);
constexpr float A21 = 0.2f;
constexpr float A31 = (float)(3.0/40.0),  A32 = (float)(9.0/40.0);
constexpr float A41 = (float)(44.0/45.0), A42 = (float)(-56.0/15.0), A43 = (float)(32.0/9.0);
constexpr float A51 = (float)(19372.0/6561.0), A52 = (float)(-25360.0/2187.0),
                A53 = (float)(64448.0/6561.0), A54 = (float)(-212.0/729.0);
constexpr float A61 = (float)(9017.0/3168.0), A62 = (float)(-355.0/33.0),
                A63 = (float)(46732.0/5247.0), A64 = (float)(49.0/176.0),
                A65 = (float)(-5103.0/18656.0);
constexpr float B1c = (float)(35.0/384.0), B3c = (float)(500.0/1113.0),
                B4c = (float)(125.0/192.0), B5c = (float)(-2187.0/6784.0),
                B6c = (float)(11.0/84.0);
constexpr float E1c = (float)(71.0/57600.0), E3c = (float)(-71.0/16695.0),
                E4c = (float)(71.0/1920.0), E5c = (float)(-17253.0/339200.0),
                E6c = (float)(22.0/525.0),  E7c = (float)(-1.0/40.0);
constexpr float RTOL = 1e-3f, ATOL = 1e-3f;

// ws layout (floats / ints)
constexpr size_t OFF_PART = 0;        // 512 floats
constexpr size_t OFF_FLAG = 512;      // 512 ints (per-tile progress)
constexpr size_t OFF_BAR  = 1024;     // 2 ints (counter, generation)
constexpr size_t OFF_TSUM = 1088;     // 576
constexpr size_t OFF_W2P  = 1664;     // 73728 ushorts = 36864 floats
constexpr size_t OFF_Y    = 38528;
constexpr size_t OFF_Y5   = OFF_Y  + (size_t)NS;
constexpr size_t OFF_K    = OFF_Y5 + (size_t)NS;   // 7*NS (k1..k7 slots)
}

__constant__ float g_cf[6][5] = {
    {A21, 0, 0, 0, 0},
    {A31, A32, 0, 0, 0},
    {A41, A42, A43, 0, 0},
    {A51, A52, A53, A54, 0},
    {A61, A62, A63, A64, A65},
    {0, 0, 0, 0, 0}};
__constant__ float g_ct[6] = {C2f, C3f, C4f, C5f, 1.0f, 1.0f};

typedef __bf16 bfrag8 __attribute__((ext_vector_type(8)));
typedef float f32x4 __attribute__((ext_vector_type(4)));

__device__ __forceinline__ unsigned short f2bf(float f) {
    unsigned u = __float_as_uint(f);
    unsigned r = u + 0x7fffu + ((u >> 16) & 1u);
    return (unsigned short)(r >> 16);
}
__device__ __forceinline__ float bf2f(unsigned short h) {
    return __uint_as_float(((unsigned)h) << 16);
}

// ---------------- init: y0 = concat(x, zeros); zero sync state ----------------
__global__ __launch_bounds__(256)
void k_init(const float* __restrict__ x, float* __restrict__ y,
            int* __restrict__ flags, int* __restrict__ bar)
{
    int idx = blockIdx.x*256 + threadIdx.x;
    int b = idx >> 13, c = (idx >> 10) & 7, p = idx & 1023;
    y[idx] = (c < 3) ? x[(size_t)(b*3 + c)*1024 + p] : 0.0f;
    if (idx < 512) flags[idx] = 0;
    if (idx < 2)   bar[idx] = 0;
}

// ---------------- prepack w2 into MFMA B-frag order + t-channel mask table ----------------
__global__ __launch_bounds__(256)
void k_prepack(const float* __restrict__ w2, unsigned short* __restrict__ w2p,
               float* __restrict__ tsum)
{
    int gid = blockIdx.x*256 + threadIdx.x;
    if (gid < 73728) {
        int j    = gid & 7;
        int lane = (gid >> 3) & 63;
        int nt   = (gid >> 9) & 3;
        int r    = gid >> 11;            // (part*2+cc)*9 + tap
        int tap  = r % 9;
        int pc   = r / 9;
        int cc   = pc & 1, part = pc >> 1;
        int oc = nt*16 + (lane & 15);
        int ic = cc*32 + (lane >> 4)*8 + j;
        float wv = w2[oc*585 + (1 + ic)*9 + tap];
        unsigned short hi = f2bf(wv);
        w2p[gid] = (part == 0) ? hi : f2bf(wv - bf2f(hi));
    }
    if (gid < 576) {
        int oc = gid & 63, combo = gid >> 6;       // 0..8
        int rcase = combo / 3, ccase = combo % 3;
        float s = 0.0f;
        for (int kh = 0; kh < 3; kh++) {
            if ((rcase == 1 && kh == 0) || (rcase == 2 && kh == 2)) continue;
            for (int kw = 0; kw < 3; kw++) {
                if ((ccase == 1 && kw == 0) || (ccase == 2 && kw == 2)) continue;
                s += w2[oc*585 + kh*3 + kw];
            }
        }
        tsum[gid] = s;
    }
}

// ---------------- the whole ODE solve: one co-resident kernel ----------------
// LDS: pool 55488 + persist 8256 = 63744 B (< 64 KB workgroup limit)
// Sync design: per-tile release/acquire flags for the 2-row halo (neighbor dep
// only); ONE custom global barrier per step for err-norm/control.
__global__ void __launch_bounds__(256, 2)
k_ode(const float* __restrict__ w1, const float* __restrict__ b1,
      const float* __restrict__ b2, const float* __restrict__ w3,
      const float* __restrict__ b3, const unsigned short* __restrict__ w2p,
      const float* __restrict__ tsumg, const float* __restrict__ wl,
      const float* __restrict__ bl, float* __restrict__ ybuf,
      float* __restrict__ y5buf, float* __restrict__ kb,
      float* __restrict__ part, int* __restrict__ flags,
      int* __restrict__ bar, float* __restrict__ out)
{
    __shared__ __align__(16) unsigned char s_pool[55488];
    __shared__ __align__(16) float s_w1t[8][64];
    __shared__ float s_w10[64], s_b1v[64];
    __shared__ __align__(16) float s_w3t[64][8];
    __shared__ float s_w30[8], s_b3v[8];
    __shared__ float s_tsum[576];
    __shared__ float s_b2v[64];
    __shared__ float s_red[256];

    const int tid = threadIdx.x;
    const int nblk = gridDim.x;
    const int wv  = tid >> 6, lane = tid & 63, l15 = lane & 15, q = lane >> 4;

    if (tid < 64) {
        s_b1v[tid] = b1[tid];
        s_w10[tid] = w1[tid*9];
        #pragma unroll
        for (int c = 0; c < 8; c++) s_w1t[c][tid] = w1[tid*9 + 1 + c];
        s_b2v[tid] = b2[tid];
        #pragma unroll
        for (int o = 0; o < 8; o++) s_w3t[tid][o] = w3[o*65 + 1 + tid];
        if (tid < 8) { s_w30[tid] = w3[tid*65]; s_b3v[tid] = b3[tid]; }
    }
    for (int i = tid; i < 576; i += 256) s_tsum[i] = tsumg[i];

    float t = 0.0f, dt = 0.1f;
    float* ya = ybuf; float* yb = y5buf;
    float* ka = kb;  float* kg = kb + 6*(size_t)NS;
    int barGen = 0;

    auto gbar = [&]() {
        __syncthreads();
        if (tid == 0) {
            __threadfence();
            int target = barGen + 1;
            int arrived = __hip_atomic_fetch_add(&bar[0], 1, __ATOMIC_ACQ_REL,
                                                 __HIP_MEMORY_SCOPE_AGENT);
            if (arrived == nblk - 1) {
                __hip_atomic_store(&bar[0], 0, __ATOMIC_RELAXED, __HIP_MEMORY_SCOPE_AGENT);
                __hip_atomic_store(&bar[1], target, __ATOMIC_RELEASE, __HIP_MEMORY_SCOPE_AGENT);
            } else {
                while (__hip_atomic_load(&bar[1], __ATOMIC_ACQUIRE,
                                         __HIP_MEMORY_SCOPE_AGENT) < target)
                    __builtin_amdgcn_s_sleep(2);
            }
        }
        __syncthreads();
        __threadfence();
        barGen++;
    };

    auto eval = [&](const float* src, int nc, const float* cf, float ctv,
                    float* kout, int mode, int gev) {
        float dtc = fminf(dt, 1.0f - t);
        float ts  = t + ctv*dtc;

        for (int tile = blockIdx.x; tile < 512; tile += nblk) {
            int b = tile >> 3, rg = tile & 7;

            // 1) zero activation pool (halo padding)
            {
                uint4 z4 = make_uint4(0u,0u,0u,0u);
                uint4* p4 = (uint4*)s_pool;
                for (int i = tid; i < 3468; i += 256) p4[i] = z4;
            }
            __syncthreads();

            // neighbor halo wait: tiles rg-1 / rg+1 must have finished eval gev-1
            if (tid == 0) {
                if (rg > 0)
                    while (__hip_atomic_load(&flags[tile-1], __ATOMIC_RELAXED,
                                             __HIP_MEMORY_SCOPE_AGENT) < gev-1)
                        __builtin_amdgcn_s_sleep(1);
                if (rg < 7)
                    while (__hip_atomic_load(&flags[tile+1], __ATOMIC_RELAXED,
                                             __HIP_MEMORY_SCOPE_AGENT) < gev-1)
                        __builtin_amdgcn_s_sleep(1);
            }
            __syncthreads();
            __threadfence();   // acquire: make neighbors' k/y5 halo writes visible

            // 2) conv1 (z-combine + 1x1 9->64 + relu) into LDS, 6 rows incl halo
            if (tid < 192) {
                int lr = tid >> 5, col = tid & 31;
                int r = rg*4 - 1 + lr;
                if ((unsigned)r < 32u) {
                    int px = (r << 5) + col;
                    float s[8] = {0,0,0,0,0,0,0,0};
                    for (int j = 0; j < nc; j++) {
                        const float* kp = (j == 0 ? ka : kb + (size_t)j*NS)
                                          + (((size_t)(b << 10) + px) << 3);
                        float4 kv0 = *(const float4*)kp;
                        float4 kv1 = *(const float4*)(kp + 4);
                        float a = cf[j];
                        s[0] += a*kv0.x; s[1] += a*kv0.y; s[2] += a*kv0.z; s[3] += a*kv0.w;
                        s[4] += a*kv1.x; s[5] += a*kv1.y; s[6] += a*kv1.z; s[7] += a*kv1.w;
                    }
                    float zz[8];
                    #pragma unroll
                    for (int c = 0; c < 8; c++)
                        zz[c] = src[((b*8 + c) << 10) + px] + dtc*s[c];
                    float acc[64];
                    #pragma unroll
                    for (int o = 0; o < 64; o++) acc[o] = fmaf(ts, s_w10[o], s_b1v[o]);
                    #pragma unroll
                    for (int c = 0; c < 8; c++) {
                        float zc = zz[c];
                        const float4* w4 = reinterpret_cast<const float4*>(&s_w1t[c][0]);
                        #pragma unroll
                        for (int qq = 0; qq < 16; qq++) {
                            float4 wq = w4[qq];
                            acc[4*qq+0] = fmaf(wq.x, zc, acc[4*qq+0]);
                            acc[4*qq+1] = fmaf(wq.y, zc, acc[4*qq+1]);
                            acc[4*qq+2] = fmaf(wq.z, zc, acc[4*qq+2]);
                            acc[4*qq+3] = fmaf(wq.w, zc, acc[4*qq+3]);
                        }
                    }
                    unsigned hibuf[32], lobuf[32];
                    #pragma unroll
                    for (int i = 0; i < 32; i++) {
                        float f0 = fmaxf(acc[2*i],   0.0f);
                        float f1 = fmaxf(acc[2*i+1], 0.0f);
                        unsigned short h0 = f2bf(f0), h1v = f2bf(f1);
                        unsigned short l0 = f2bf(f0 - bf2f(h0)), l1 = f2bf(f1 - bf2f(h1v));
                        hibuf[i] = (unsigned)h0 | ((unsigned)h1v << 16);
                        lobuf[i] = (unsigned)l0 | ((unsigned)l1 << 16);
                    }
                    int pxi = lr*34 + col + 1;
                    uint4* d = (uint4*)(s_pool + (size_t)pxi*272);
                    const uint4* hbv = (const uint4*)hibuf;
                    const uint4* lbv = (const uint4*)lobuf;
                    #pragma unroll
                    for (int i = 0; i < 8; i++) d[i] = hbv[i];
                    #pragma unroll
                    for (int i = 0; i < 8; i++) d[8 + i] = lbv[i];
                }
            }
            __syncthreads();

            // 3) conv2: 3x3 65->64 split-bf16 MFMA
            f32x4 acc2[2][4];
            #pragma unroll
            for (int mt = 0; mt < 2; mt++)
                #pragma unroll
                for (int nt = 0; nt < 4; nt++) acc2[mt][nt] = (f32x4){0.f,0.f,0.f,0.f};

            for (int cc = 0; cc < 2; cc++) {
                const unsigned short* wp_hi = w2p + (size_t)(cc*9)*2048;
                const unsigned short* wp_lo = w2p + (size_t)((2 + cc)*9)*2048;
                #pragma unroll 1
                for (int kh = 0; kh < 3; kh++) {
                    #pragma unroll
                    for (int kw = 0; kw < 3; kw++) {
                        int tap = kh*3 + kw;
                        bfrag8 bh[4], bl[4];
                        #pragma unroll
                        for (int nt = 0; nt < 4; nt++) {
                            bh[nt] = *(const bfrag8*)(wp_hi + (size_t)(tap*4 + nt)*512 + lane*8);
                            bl[nt] = *(const bfrag8*)(wp_lo + (size_t)(tap*4 + nt)*512 + lane*8);
                        }
                        int lr = wv + kh;
                        #pragma unroll
                        for (int mt = 0; mt < 2; mt++) {
                            int lc = mt*16 + l15 + kw;
                            const unsigned char* pxp = s_pool
                                + (size_t)(lr*34 + lc)*272 + cc*64 + q*16;
                            bfrag8 ah = *(const bfrag8*)pxp;
                            bfrag8 al = *(const bfrag8*)(pxp + 128);
                            #pragma unroll
                            for (int nt = 0; nt < 4; nt++) {
                                acc2[mt][nt] = __builtin_amdgcn_mfma_f32_16x16x32_bf16(ah, bh[nt], acc2[mt][nt], 0, 0, 0);
                                acc2[mt][nt] = __builtin_amdgcn_mfma_f32_16x16x32_bf16(ah, bl[nt], acc2[mt][nt], 0, 0, 0);
                                acc2[mt][nt] = __builtin_amdgcn_mfma_f32_16x16x32_bf16(al, bh[nt], acc2[mt][nt], 0, 0, 0);
                            }
                        }
                    }
                }
            }
            __syncthreads();

            // 4) epilogue: t-channel + bias + relu -> LDS h2, oc-major stride 129
            {
                float* s_h2 = (float*)s_pool;
                int r_out = rg*4 + wv;
                int rcase = (r_out == 0) ? 1 : ((r_out == 31) ? 2 : 0);
                #pragma unroll
                for (int mt = 0; mt < 2; mt++) {
                    #pragma unroll
                    for (int reg = 0; reg < 4; reg++) {
                        int c = mt*16 + q*4 + reg;
                        int ccase = (c == 0) ? 1 : ((c == 31) ? 2 : 0);
                        const float* tsp = s_tsum + (rcase*3 + ccase)*64;
                        int pxl = wv*32 + c;
                        #pragma unroll
                        for (int nt = 0; nt < 4; nt++) {
                            int oc = nt*16 + l15;
                            s_h2[oc*129 + pxl] =
                                fmaxf(acc2[mt][nt][reg] + ts*tsp[oc] + s_b2v[oc], 0.0f);
                        }
                    }
                }
            }
            __syncthreads();

            // 5) conv3 (1x1 65->8) + mode epilogues
            if (tid < 128) {
                const float* s_h2 = (const float*)s_pool;
                float a3[8];
                #pragma unroll
                for (int o = 0; o < 8; o++) a3[o] = fmaf(ts, s_w30[o], s_b3v[o]);
                #pragma unroll 8
                for (int c = 0; c < 64; c++) {
                    float xv = s_h2[c*129 + tid];
                    const float4* w4 = (const float4*)&s_w3t[c][0];
                    float4 wA = w4[0], wB = w4[1];
                    a3[0] = fmaf(wA.x, xv, a3[0]);
                    a3[1] = fmaf(wA.y, xv, a3[1]);
                    a3[2] = fmaf(wA.z, xv, a3[2]);
                    a3[3] = fmaf(wA.w, xv, a3[3]);
                    a3[4] = fmaf(wB.x, xv, a3[4]);
                    a3[5] = fmaf(wB.y, xv, a3[5]);
                    a3[6] = fmaf(wB.z, xv, a3[6]);
                    a3[7] = fmaf(wB.w, xv, a3[7]);
                }
                int px = rg*128 + tid;
                size_t pb8 = ((size_t)(b << 10) + px) << 3;
                *(float4*)(kout + pb8)     = make_float4(a3[0], a3[1], a3[2], a3[3]);
                *(float4*)(kout + pb8 + 4) = make_float4(a3[4], a3[5], a3[6], a3[7]);
                if (mode == 1) {
                    const float* k1p = ka + pb8;
                    const float* k3p = kb + 2*(size_t)NS + pb8;
                    const float* k4p = kb + 3*(size_t)NS + pb8;
                    const float* k5p = kb + 4*(size_t)NS + pb8;
                    #pragma unroll
                    for (int c = 0; c < 8; c++) {
                        size_t id = ((size_t)(b*8 + c) << 10) + px;
                        yb[id] = ya[id] + dtc*(B1c*k1p[c] + B3c*k3p[c] + B4c*k4p[c]
                                               + B5c*k5p[c] + B6c*a3[c]);
                    }
                } else if (mode == 2) {
                    const float* k1p = ka + pb8;
                    const float* k3p = kb + 2*(size_t)NS + pb8;
                    const float* k4p = kb + 3*(size_t)NS + pb8;
                    const float* k5p = kb + 4*(size_t)NS + pb8;
                    const float* k6p = kb + 5*(size_t)NS + pb8;
                    float ls = 0.0f;
                    #pragma unroll
                    for (int c = 0; c < 8; c++) {
                        size_t id = ((size_t)(b*8 + c) << 10) + px;
                        float e = dtc*(E1c*k1p[c] + E3c*k3p[c] + E4c*k4p[c]
                                       + E5c*k5p[c] + E6c*k6p[c] + E7c*a3[c]);
                        float tol = ATOL + RTOL*fmaxf(fabsf(ya[id]), fabsf(yb[id]));
                        float rr = e / tol;
                        ls += rr*rr;
                    }
                    s_red[tid] = ls;
                }
            }
            if (mode == 2) {
                if (tid >= 128) s_red[tid] = 0.0f;
                __syncthreads();
                for (int sft = 128; sft > 0; sft >>= 1) {
                    if (tid < sft) s_red[tid] += s_red[tid + sft];
                    __syncthreads();
                }
                if (tid == 0) part[tile] = s_red[0];
            }

            // signal: this tile finished eval gev (k/y5/partial writes visible)
            __syncthreads();
            if (tid == 0) {
                __threadfence();   // release own k/y5 writes to agent scope
                __hip_atomic_store(&flags[tile], gev, __ATOMIC_RELEASE,
                                   __HIP_MEMORY_SCOPE_AGENT);
            }
        }
    };

    int gev = 1;
    eval(ya, 0, g_cf[5], 0.0f, ka, 0, gev);   // k1 = f(t0, y0)
    gev++;

    for (int st = 0; st < 24; st++) {
        if (t >= 1.0f - 1e-7f) break;
        for (int e = 0; e < 6; e++) {
            int nc = (e < 5) ? e + 1 : 0;
            const float* src = (e == 5) ? yb : ya;
            float* kout = (e < 5) ? kb + (size_t)(e + 1)*NS : kg;
            int mode = (e == 4) ? 1 : ((e == 5) ? 2 : 0);
            eval(src, nc, g_cf[e], g_ct[e], kout, mode, gev);
            gev++;
        }
        gbar();   // one global barrier per step: all partials visible

        // control: every block reduces the same 512 partials identically
        float v = part[tid] + part[tid + 256];
        s_red[tid] = v;
        __syncthreads();
        for (int sft = 128; sft > 0; sft >>= 1) {
            if (tid < sft) s_red[tid] += s_red[tid + sft];
            __syncthreads();
        }
        float red0 = s_red[0];
        __syncthreads();
        float err_norm = sqrtf(red0 / (float)NS);
        float dtc = fminf(dt, 1.0f - t);
        bool adv = (err_norm <= 1.0f);
        if (adv) {
            t = t + dtc;
            float* tmp = ya; ya = yb; yb = tmp;   // y <- y5
            tmp = ka; ka = kg; kg = tmp;          // k1 <- k7 (FSAL)
        }
        float safe = fmaxf(err_norm, 1e-10f);
        float factor = fminf(fmaxf(0.9f*powf(safe, -0.2f), 0.2f), 10.0f);
        dt = dtc*factor;
    }

    // final linear head
    __syncthreads();
    for (int bh = blockIdx.x; bh < 64; bh += nblk) {
        float* s_hred = (float*)s_pool;   // 10*256 floats overlay
        float acc[10];
        #pragma unroll
        for (int m = 0; m < 10; m++) acc[m] = 0.0f;
        for (int f = tid; f < 8192; f += 256) {
            float yv = ya[(size_t)bh*8192 + f];
            #pragma unroll
            for (int m = 0; m < 10; m++) acc[m] = fmaf(yv, wl[(size_t)m*8192 + f], acc[m]);
        }
        #pragma unroll
        for (int m = 0; m < 10; m++) s_hred[m*256 + tid] = acc[m];
        __syncthreads();
        for (int sft = 128; sft > 0; sft >>= 1) {
            if (tid < sft) {
                #pragma unroll
                for (int m = 0; m < 10; m++)
                    s_hred[m*256 + tid] += s_hred[m*256 + tid + sft];
            }
            __syncthreads();
        }
        if (tid < 10) out[bh*10 + tid] = s_hred[tid*256] + bl[tid];
        __syncthreads();
    }
}

// ---------------- host ----------------
extern "C" void kernel_launch(void* const* d_in, const int* in_sizes, int n_in,
                              void* d_out, int out_size, void* d_ws, size_t ws_size,
                              hipStream_t stream)
{
    const float* x  = (const float*)d_in[0];
    const float* w1 = (const float*)d_in[1];
    const float* b1 = (const float*)d_in[2];
    const float* w2 = (const float*)d_in[3];
    const float* b2 = (const float*)d_in[4];
    const float* w3 = (const float*)d_in[5];
    const float* b3 = (const float*)d_in[6];
    const float* wl = (const float*)d_in[7];
    const float* bl = (const float*)d_in[8];
    float* out = (float*)d_out;

    float* F = (float*)d_ws;
    float* part = F + OFF_PART;
    int*   flags = (int*)(F + OFF_FLAG);
    int*   bar   = (int*)(F + OFF_BAR);
    float* tsum = F + OFF_TSUM;
    unsigned short* w2p = (unsigned short*)(F + OFF_W2P);
    float* y    = F + OFF_Y;
    float* y5   = F + OFF_Y5;
    float* kbp  = F + OFF_K;

    k_init<<<NS/256, 256, 0, stream>>>(x, y, flags, bar);
    k_prepack<<<288, 256, 0, stream>>>(w2, w2p, tsum);

    // size the co-resident grid to guaranteed capacity
    int maxb = 0;
    if (hipOccupancyMaxActiveBlocksPerMultiprocessor(&maxb,
            reinterpret_cast<const void*>(k_ode), 256, 0) != hipSuccess || maxb < 1)
        maxb = 1;
    int cus = 256;
    {
        int dev = 0;
        hipGetDevice(&dev);
        hipDeviceProp_t prop;
        if (hipGetDeviceProperties(&prop, dev) == hipSuccess && prop.multiProcessorCount > 0)
            cus = prop.multiProcessorCount;
    }
    long cap = (long)maxb * (long)cus;
    int gridn = (int)((cap < 512) ? cap : 512);
    if (gridn < 16) gridn = 16;   // tiles owned by one block must never be adjacent

    void* args[] = {
        (void*)&w1, (void*)&b1, (void*)&b2, (void*)&w3, (void*)&b3,
        (void*)&w2p, (void*)&tsum, (void*)&wl, (void*)&bl,
        (void*)&y, (void*)&y5, (void*)&kbp, (void*)&part,
        (void*)&flags, (void*)&bar, (void*)&out
    };
    hipLaunchCooperativeKernel((void*)k_ode, dim3(gridn), dim3(256), args, 0, stream);
}

// Round 6
// 1192.642 us; speedup vs baseline: 1.4124x; 1.4124x over previous
//
#include <hip/hip_runtime.h>
#include <hip/hip_cooperative_groups.h>
#include <math.h>

namespace cg = cooperative_groups;

namespace {
constexpr int BN = 64;
constexpr int HW = 1024;
constexpr int NS = BN*8*HW;      // 524288

constexpr float C2f = 0.2f, C3f = 0.3f, C4f = 0.8f, C5f = (float)(8.0/9.0);
constexpr float A21 = 0.2f;
constexpr float A31 = (float)(3.0/40.0),  A32 = (float)(9.0/40.0);
constexpr float A41 = (float)(44.0/45.0), A42 = (float)(-56.0/15.0), A43 = (float)(32.0/9.0);
constexpr float A51 = (float)(19372.0/6561.0), A52 = (float)(-25360.0/2187.0),
                A53 = (float)(64448.0/6561.0), A54 = (float)(-212.0/729.0);
constexpr float A61 = (float)(9017.0/3168.0), A62 = (float)(-355.0/33.0),
                A63 = (float)(46732.0/5247.0), A64 = (float)(49.0/176.0),
                A65 = (float)(-5103.0/18656.0);
constexpr float B1c = (float)(35.0/384.0), B3c = (float)(500.0/1113.0),
                B4c = (float)(125.0/192.0), B5c = (float)(-2187.0/6784.0),
                B6c = (float)(11.0/84.0);
constexpr float E1c = (float)(71.0/57600.0), E3c = (float)(-71.0/16695.0),
                E4c = (float)(71.0/1920.0), E5c = (float)(-17253.0/339200.0),
                E6c = (float)(22.0/525.0),  E7c = (float)(-1.0/40.0);
constexpr float RTOL = 1e-3f, ATOL = 1e-3f;

// ws layout (floats)
constexpr size_t OFF_PART = 0;        // 512
constexpr size_t OFF_TSUM = 512;      // 576
constexpr size_t OFF_W2P  = 1088;     // 73728 ushorts = 36864 floats
constexpr size_t OFF_Y    = 37952;
constexpr size_t OFF_Y5   = OFF_Y  + (size_t)NS;
constexpr size_t OFF_K    = OFF_Y5 + (size_t)NS;   // 7*NS (k1..k7 slots)
}

__constant__ float g_cf[6][5] = {
    {A21, 0, 0, 0, 0},
    {A31, A32, 0, 0, 0},
    {A41, A42, A43, 0, 0},
    {A51, A52, A53, A54, 0},
    {A61, A62, A63, A64, A65},
    {0, 0, 0, 0, 0}};
__constant__ float g_ct[6] = {C2f, C3f, C4f, C5f, 1.0f, 1.0f};

typedef __bf16 bfrag8 __attribute__((ext_vector_type(8)));
typedef float f32x4 __attribute__((ext_vector_type(4)));

__device__ __forceinline__ unsigned short f2bf(float f) {
    unsigned u = __float_as_uint(f);
    unsigned r = u + 0x7fffu + ((u >> 16) & 1u);
    return (unsigned short)(r >> 16);
}
__device__ __forceinline__ float bf2f(unsigned short h) {
    return __uint_as_float(((unsigned)h) << 16);
}

// ---------------- init: y0 = concat(x, zeros) ----------------
__global__ __launch_bounds__(256)
void k_init(const float* __restrict__ x, float* __restrict__ y)
{
    int idx = blockIdx.x*256 + threadIdx.x;
    int b = idx >> 13, c = (idx >> 10) & 7, p = idx & 1023;
    y[idx] = (c < 3) ? x[(size_t)(b*3 + c)*1024 + p] : 0.0f;
}

// ---------------- prepack w2 into MFMA B-frag order + t-channel mask table ----------------
__global__ __launch_bounds__(256)
void k_prepack(const float* __restrict__ w2, unsigned short* __restrict__ w2p,
               float* __restrict__ tsum)
{
    int gid = blockIdx.x*256 + threadIdx.x;
    if (gid < 73728) {
        int j    = gid & 7;
        int lane = (gid >> 3) & 63;
        int nt   = (gid >> 9) & 3;
        int r    = gid >> 11;            // (part*2+cc)*9 + tap
        int tap  = r % 9;
        int pc   = r / 9;
        int cc   = pc & 1, part = pc >> 1;
        int oc = nt*16 + (lane & 15);
        int ic = cc*32 + (lane >> 4)*8 + j;
        float wv = w2[oc*585 + (1 + ic)*9 + tap];
        unsigned short hi = f2bf(wv);
        w2p[gid] = (part == 0) ? hi : f2bf(wv - bf2f(hi));
    }
    if (gid < 576) {
        int oc = gid & 63, combo = gid >> 6;       // 0..8
        int rcase = combo / 3, ccase = combo % 3;
        float s = 0.0f;
        for (int kh = 0; kh < 3; kh++) {
            if ((rcase == 1 && kh == 0) || (rcase == 2 && kh == 2)) continue;
            for (int kw = 0; kw < 3; kw++) {
                if ((ccase == 1 && kw == 0) || (ccase == 2 && kw == 2)) continue;
                s += w2[oc*585 + kh*3 + kw];
            }
        }
        tsum[gid] = s;
    }
}

// ---------------- the whole ODE solve: one cooperative kernel ----------------
// LDS budget: pool 55488 + persist 8256 = 63744 B  (< 64 KB workgroup limit)
// conv2 work split: wave = (row-pair, oc-pair) quadrant -> each wave loads only
// 2 of 4 B-fragment groups (halves L2 weight traffic vs row-only split).
__global__ void __launch_bounds__(256, 2)
k_ode(const float* __restrict__ w1, const float* __restrict__ b1,
      const float* __restrict__ b2, const float* __restrict__ w3,
      const float* __restrict__ b3, const unsigned short* __restrict__ w2p,
      const float* __restrict__ tsumg, const float* __restrict__ wl,
      const float* __restrict__ bl, float* __restrict__ ybuf,
      float* __restrict__ y5buf, float* __restrict__ kb,
      float* __restrict__ part, float* __restrict__ out)
{
    cg::grid_group grid = cg::this_grid();

    // activation pool: 6*34 px, 272 B/px = [hi ch0-31 | hi ch32-63 | lo ch0-31 | lo ch32-63 | 16B pad]
    __shared__ __align__(16) unsigned char s_pool[55488];
    __shared__ __align__(16) float s_w1t[8][64];
    __shared__ float s_w10[64], s_b1v[64];
    __shared__ __align__(16) float s_w3t[64][8];
    __shared__ float s_w30[8], s_b3v[8];
    __shared__ float s_tsum[576];
    __shared__ float s_b2v[64];
    __shared__ float s_red[256];

    const int tid = threadIdx.x;
    const int nblk = gridDim.x;
    const int lane = tid & 63, l15 = lane & 15, q = lane >> 4;
    const int rp = tid >> 7;          // row-pair: rows rp*2, rp*2+1 of the 4-row tile
    const int np = (tid >> 6) & 1;    // oc-pair:  nt = np*2, np*2+1

    if (tid < 64) {
        s_b1v[tid] = b1[tid];
        s_w10[tid] = w1[tid*9];
        #pragma unroll
        for (int c = 0; c < 8; c++) s_w1t[c][tid] = w1[tid*9 + 1 + c];
        s_b2v[tid] = b2[tid];
        #pragma unroll
        for (int o = 0; o < 8; o++) s_w3t[tid][o] = w3[o*65 + 1 + tid];
        if (tid < 8) { s_w30[tid] = w3[tid*65]; s_b3v[tid] = b3[tid]; }
    }
    for (int i = tid; i < 576; i += 256) s_tsum[i] = tsumg[i];

    float t = 0.0f, dt = 0.1f;
    float* ya = ybuf; float* yb = y5buf;
    float* ka = kb;  float* kg = kb + 6*(size_t)NS;

    auto eval = [&](const float* src, int nc, const float* cf, float ctv,
                    float* kout, int mode) {
        float dtc = fminf(dt, 1.0f - t);
        float ts  = t + ctv*dtc;

        for (int tile = blockIdx.x; tile < 512; tile += nblk) {
            int b = tile >> 3, rg = tile & 7;

            // 1) zero activation pool (halo padding)
            {
                uint4 z4 = make_uint4(0u,0u,0u,0u);
                uint4* p4 = (uint4*)s_pool;
                for (int i = tid; i < 3468; i += 256) p4[i] = z4;
            }
            __syncthreads();

            // 2) conv1 (z-combine + 1x1 9->64 + relu) into LDS, 6 rows incl halo
            if (tid < 192) {
                int lr = tid >> 5, col = tid & 31;
                int r = rg*4 - 1 + lr;
                if ((unsigned)r < 32u) {
                    int px = (r << 5) + col;
                    float s[8] = {0,0,0,0,0,0,0,0};
                    for (int j = 0; j < nc; j++) {
                        const float* kp = (j == 0 ? ka : kb + (size_t)j*NS)
                                          + (((size_t)(b << 10) + px) << 3);
                        float4 kv0 = *(const float4*)kp;
                        float4 kv1 = *(const float4*)(kp + 4);
                        float a = cf[j];
                        s[0] += a*kv0.x; s[1] += a*kv0.y; s[2] += a*kv0.z; s[3] += a*kv0.w;
                        s[4] += a*kv1.x; s[5] += a*kv1.y; s[6] += a*kv1.z; s[7] += a*kv1.w;
                    }
                    float zz[8];
                    #pragma unroll
                    for (int c = 0; c < 8; c++)
                        zz[c] = src[((b*8 + c) << 10) + px] + dtc*s[c];
                    float acc[64];
                    #pragma unroll
                    for (int o = 0; o < 64; o++) acc[o] = fmaf(ts, s_w10[o], s_b1v[o]);
                    #pragma unroll
                    for (int c = 0; c < 8; c++) {
                        float zc = zz[c];
                        const float4* w4 = reinterpret_cast<const float4*>(&s_w1t[c][0]);
                        #pragma unroll
                        for (int qq = 0; qq < 16; qq++) {
                            float4 wq = w4[qq];
                            acc[4*qq+0] = fmaf(wq.x, zc, acc[4*qq+0]);
                            acc[4*qq+1] = fmaf(wq.y, zc, acc[4*qq+1]);
                            acc[4*qq+2] = fmaf(wq.z, zc, acc[4*qq+2]);
                            acc[4*qq+3] = fmaf(wq.w, zc, acc[4*qq+3]);
                        }
                    }
                    unsigned hibuf[32], lobuf[32];
                    #pragma unroll
                    for (int i = 0; i < 32; i++) {
                        float f0 = fmaxf(acc[2*i],   0.0f);
                        float f1 = fmaxf(acc[2*i+1], 0.0f);
                        unsigned short h0 = f2bf(f0), h1v = f2bf(f1);
                        unsigned short l0 = f2bf(f0 - bf2f(h0)), l1 = f2bf(f1 - bf2f(h1v));
                        hibuf[i] = (unsigned)h0 | ((unsigned)h1v << 16);
                        lobuf[i] = (unsigned)l0 | ((unsigned)l1 << 16);
                    }
                    int pxi = lr*34 + col + 1;
                    uint4* d = (uint4*)(s_pool + (size_t)pxi*272);
                    const uint4* hbv = (const uint4*)hibuf;
                    const uint4* lbv = (const uint4*)lobuf;
                    #pragma unroll
                    for (int i = 0; i < 8; i++) d[i] = hbv[i];
                    #pragma unroll
                    for (int i = 0; i < 8; i++) d[8 + i] = lbv[i];
                }
            }
            __syncthreads();

            // 3) conv2: 3x3 65->64 split-bf16 MFMA, quadrant split
            f32x4 acc2[2][2][2];   // [ri][ch][nn]
            #pragma unroll
            for (int ri = 0; ri < 2; ri++)
                #pragma unroll
                for (int ch = 0; ch < 2; ch++)
                    #pragma unroll
                    for (int nn = 0; nn < 2; nn++)
                        acc2[ri][ch][nn] = (f32x4){0.f,0.f,0.f,0.f};

            for (int cc = 0; cc < 2; cc++) {
                const unsigned short* wp_hi = w2p + (size_t)(cc*9)*2048;
                const unsigned short* wp_lo = w2p + (size_t)((2 + cc)*9)*2048;
                #pragma unroll 1
                for (int kh = 0; kh < 3; kh++) {
                    #pragma unroll
                    for (int kw = 0; kw < 3; kw++) {
                        int tap = kh*3 + kw;
                        bfrag8 bh[2], bl[2];
                        #pragma unroll
                        for (int nn = 0; nn < 2; nn++) {
                            int nt = np*2 + nn;
                            bh[nn] = *(const bfrag8*)(wp_hi + (size_t)(tap*4 + nt)*512 + lane*8);
                            bl[nn] = *(const bfrag8*)(wp_lo + (size_t)(tap*4 + nt)*512 + lane*8);
                        }
                        #pragma unroll
                        for (int ri = 0; ri < 2; ri++) {
                            int lr = rp*2 + ri + kh;
                            bfrag8 ah[2], al[2];
                            #pragma unroll
                            for (int ch = 0; ch < 2; ch++) {
                                int lc = ch*16 + l15 + kw;
                                const unsigned char* pxp = s_pool
                                    + (size_t)(lr*34 + lc)*272 + cc*64 + q*16;
                                ah[ch] = *(const bfrag8*)pxp;
                                al[ch] = *(const bfrag8*)(pxp + 128);
                            }
                            // product passes ordered so same-acc MFMAs are 4 apart
                            #pragma unroll
                            for (int ch = 0; ch < 2; ch++)
                                #pragma unroll
                                for (int nn = 0; nn < 2; nn++)
                                    acc2[ri][ch][nn] = __builtin_amdgcn_mfma_f32_16x16x32_bf16(
                                        ah[ch], bh[nn], acc2[ri][ch][nn], 0, 0, 0);
                            #pragma unroll
                            for (int ch = 0; ch < 2; ch++)
                                #pragma unroll
                                for (int nn = 0; nn < 2; nn++)
                                    acc2[ri][ch][nn] = __builtin_amdgcn_mfma_f32_16x16x32_bf16(
                                        ah[ch], bl[nn], acc2[ri][ch][nn], 0, 0, 0);
                            #pragma unroll
                            for (int ch = 0; ch < 2; ch++)
                                #pragma unroll
                                for (int nn = 0; nn < 2; nn++)
                                    acc2[ri][ch][nn] = __builtin_amdgcn_mfma_f32_16x16x32_bf16(
                                        al[ch], bh[nn], acc2[ri][ch][nn], 0, 0, 0);
                        }
                    }
                }
            }
            __syncthreads();   // before h2 overlay on pool

            // 4) epilogue: t-channel + bias + relu -> LDS h2, oc-major stride 129
            {
                float* s_h2 = (float*)s_pool;
                #pragma unroll
                for (int ri = 0; ri < 2; ri++) {
                    int lrow = rp*2 + ri;
                    int r_out = rg*4 + lrow;
                    int rcase = (r_out == 0) ? 1 : ((r_out == 31) ? 2 : 0);
                    #pragma unroll
                    for (int ch = 0; ch < 2; ch++) {
                        #pragma unroll
                        for (int reg = 0; reg < 4; reg++) {
                            int c = ch*16 + q*4 + reg;
                            int ccase = (c == 0) ? 1 : ((c == 31) ? 2 : 0);
                            const float* tsp = s_tsum + (rcase*3 + ccase)*64;
                            int pxl = lrow*32 + c;
                            #pragma unroll
                            for (int nn = 0; nn < 2; nn++) {
                                int oc = (np*2 + nn)*16 + l15;
                                s_h2[oc*129 + pxl] =
                                    fmaxf(acc2[ri][ch][nn][reg] + ts*tsp[oc] + s_b2v[oc], 0.0f);
                            }
                        }
                    }
                }
            }
            __syncthreads();

            // 5) conv3 (1x1 65->8) + mode epilogues
            if (tid < 128) {
                const float* s_h2 = (const float*)s_pool;
                float a3[8];
                #pragma unroll
                for (int o = 0; o < 8; o++) a3[o] = fmaf(ts, s_w30[o], s_b3v[o]);
                #pragma unroll 8
                for (int c = 0; c < 64; c++) {
                    float xv = s_h2[c*129 + tid];
                    const float4* w4 = (const float4*)&s_w3t[c][0];
                    float4 wA = w4[0], wB = w4[1];
                    a3[0] = fmaf(wA.x, xv, a3[0]);
                    a3[1] = fmaf(wA.y, xv, a3[1]);
                    a3[2] = fmaf(wA.z, xv, a3[2]);
                    a3[3] = fmaf(wA.w, xv, a3[3]);
                    a3[4] = fmaf(wB.x, xv, a3[4]);
                    a3[5] = fmaf(wB.y, xv, a3[5]);
                    a3[6] = fmaf(wB.z, xv, a3[6]);
                    a3[7] = fmaf(wB.w, xv, a3[7]);
                }
                int px = rg*128 + tid;
                size_t pb8 = ((size_t)(b << 10) + px) << 3;
                *(float4*)(kout + pb8)     = make_float4(a3[0], a3[1], a3[2], a3[3]);
                *(float4*)(kout + pb8 + 4) = make_float4(a3[4], a3[5], a3[6], a3[7]);
                if (mode == 1) {
                    const float* k1p = ka + pb8;
                    const float* k3p = kb + 2*(size_t)NS + pb8;
                    const float* k4p = kb + 3*(size_t)NS + pb8;
                    const float* k5p = kb + 4*(size_t)NS + pb8;
                    #pragma unroll
                    for (int c = 0; c < 8; c++) {
                        size_t id = ((size_t)(b*8 + c) << 10) + px;
                        yb[id] = ya[id] + dtc*(B1c*k1p[c] + B3c*k3p[c] + B4c*k4p[c]
                                               + B5c*k5p[c] + B6c*a3[c]);
                    }
                } else if (mode == 2) {
                    const float* k1p = ka + pb8;
                    const float* k3p = kb + 2*(size_t)NS + pb8;
                    const float* k4p = kb + 3*(size_t)NS + pb8;
                    const float* k5p = kb + 4*(size_t)NS + pb8;
                    const float* k6p = kb + 5*(size_t)NS + pb8;
                    float ls = 0.0f;
                    #pragma unroll
                    for (int c = 0; c < 8; c++) {
                        size_t id = ((size_t)(b*8 + c) << 10) + px;
                        float e = dtc*(E1c*k1p[c] + E3c*k3p[c] + E4c*k4p[c]
                                       + E5c*k5p[c] + E6c*k6p[c] + E7c*a3[c]);
                        float tol = ATOL + RTOL*fmaxf(fabsf(ya[id]), fabsf(yb[id]));
                        float rr = e / tol;
                        ls += rr*rr;
                    }
                    s_red[tid] = ls;
                }
            }
            if (mode == 2) {
                if (tid >= 128) s_red[tid] = 0.0f;
                __syncthreads();
                for (int sft = 128; sft > 0; sft >>= 1) {
                    if (tid < sft) s_red[tid] += s_red[tid + sft];
                    __syncthreads();
                }
                if (tid == 0) part[tile] = s_red[0];
            }
            __syncthreads();   // protect pool before next tile
        }
        grid.sync();
    };

    // k1 = f(t0, y0)
    eval(ya, 0, g_cf[5], 0.0f, ka, 0);

    for (int st = 0; st < 24; st++) {
        if (t >= 1.0f - 1e-7f) break;
        for (int e = 0; e < 6; e++) {
            int nc = (e < 5) ? e + 1 : 0;
            const float* src = (e == 5) ? yb : ya;
            float* kout = (e < 5) ? kb + (size_t)(e + 1)*NS : kg;
            int mode = (e == 4) ? 1 : ((e == 5) ? 2 : 0);
            eval(src, nc, g_cf[e], g_ct[e], kout, mode);
        }
        // control: every block reduces the same 512 partials identically
        float v = part[tid] + part[tid + 256];
        s_red[tid] = v;
        __syncthreads();
        for (int sft = 128; sft > 0; sft >>= 1) {
            if (tid < sft) s_red[tid] += s_red[tid + sft];
            __syncthreads();
        }
        float red0 = s_red[0];
        __syncthreads();
        float err_norm = sqrtf(red0 / (float)NS);
        float dtc = fminf(dt, 1.0f - t);
        bool adv = (err_norm <= 1.0f);
        if (adv) {
            t = t + dtc;
            float* tmp = ya; ya = yb; yb = tmp;   // y <- y5
            tmp = ka; ka = kg; kg = tmp;          // k1 <- k7 (FSAL)
        }
        float safe = fmaxf(err_norm, 1e-10f);
        float factor = fminf(fmaxf(0.9f*powf(safe, -0.2f), 0.2f), 10.0f);
        dt = dtc*factor;
    }

    // final linear head
    __syncthreads();
    for (int bh = blockIdx.x; bh < 64; bh += nblk) {
        float* s_hred = (float*)s_pool;   // 10*256 floats overlay
        float acc[10];
        #pragma unroll
        for (int m = 0; m < 10; m++) acc[m] = 0.0f;
        for (int f = tid; f < 8192; f += 256) {
            float yv = ya[(size_t)bh*8192 + f];
            #pragma unroll
            for (int m = 0; m < 10; m++) acc[m] = fmaf(yv, wl[(size_t)m*8192 + f], acc[m]);
        }
        #pragma unroll
        for (int m = 0; m < 10; m++) s_hred[m*256 + tid] = acc[m];
        __syncthreads();
        for (int sft = 128; sft > 0; sft >>= 1) {
            if (tid < sft) {
                #pragma unroll
                for (int m = 0; m < 10; m++)
                    s_hred[m*256 + tid] += s_hred[m*256 + tid + sft];
            }
            __syncthreads();
        }
        if (tid < 10) out[bh*10 + tid] = s_hred[tid*256] + bl[tid];
        __syncthreads();
    }
}

// ---------------- host ----------------
extern "C" void kernel_launch(void* const* d_in, const int* in_sizes, int n_in,
                              void* d_out, int out_size, void* d_ws, size_t ws_size,
                              hipStream_t stream)
{
    const float* x  = (const float*)d_in[0];
    const float* w1 = (const float*)d_in[1];
    const float* b1 = (const float*)d_in[2];
    const float* w2 = (const float*)d_in[3];
    const float* b2 = (const float*)d_in[4];
    const float* w3 = (const float*)d_in[5];
    const float* b3 = (const float*)d_in[6];
    const float* wl = (const float*)d_in[7];
    const float* bl = (const float*)d_in[8];
    float* out = (float*)d_out;

    float* F = (float*)d_ws;
    float* part = F + OFF_PART;
    float* tsum = F + OFF_TSUM;
    unsigned short* w2p = (unsigned short*)(F + OFF_W2P);
    float* y    = F + OFF_Y;
    float* y5   = F + OFF_Y5;
    float* kbp  = F + OFF_K;

    k_init<<<NS/256, 256, 0, stream>>>(x, y);
    k_prepack<<<288, 256, 0, stream>>>(w2, w2p, tsum);

    // size the cooperative grid to guaranteed co-residency
    int maxb = 0;
    if (hipOccupancyMaxActiveBlocksPerMultiprocessor(&maxb,
            reinterpret_cast<const void*>(k_ode), 256, 0) != hipSuccess || maxb < 1)
        maxb = 1;
    int cus = 256;
    {
        int dev = 0;
        hipGetDevice(&dev);
        hipDeviceProp_t prop;
        if (hipGetDeviceProperties(&prop, dev) == hipSuccess && prop.multiProcessorCount > 0)
            cus = prop.multiProcessorCount;
    }
    long cap = (long)maxb * (long)cus;
    int gridn = (int)((cap < 512) ? cap : 512);
    if (gridn < 1) gridn = 1;

    void* args[] = {
        (void*)&w1, (void*)&b1, (void*)&b2, (void*)&w3, (void*)&b3,
        (void*)&w2p, (void*)&tsum, (void*)&wl, (void*)&bl,
        (void*)&y, (void*)&y5, (void*)&kbp, (void*)&part, (void*)&out
    };
    hipLaunchCooperativeKernel((void*)k_ode, dim3(gridn), dim3(256), args, 0, stream);
}

// Round 7
// 768.830 us; speedup vs baseline: 2.1909x; 1.5512x over previous
//
#include <hip/hip_runtime.h>
#include <math.h>

namespace {
constexpr int BN = 64;
constexpr int HW = 1024;
constexpr int NS = BN*8*HW;      // 524288

constexpr float C2f = 0.2f, C3f = 0.3f, C4f = 0.8f, C5f = (float)(8.0/9.0);
constexpr float A21 = 0.2f;
constexpr float A31 = (float)(3.0/40.0),  A32 = (float)(9.0/40.0);
constexpr float A41 = (float)(44.0/45.0), A42 = (float)(-56.0/15.0), A43 = (float)(32.0/9.0);
constexpr float A51 = (float)(19372.0/6561.0), A52 = (float)(-25360.0/2187.0),
                A53 = (float)(64448.0/6561.0), A54 = (float)(-212.0/729.0);
constexpr float A61 = (float)(9017.0/3168.0), A62 = (float)(-355.0/33.0),
                A63 = (float)(46732.0/5247.0), A64 = (float)(49.0/176.0),
                A65 = (float)(-5103.0/18656.0);
constexpr float B1c = (float)(35.0/384.0), B3c = (float)(500.0/1113.0),
                B4c = (float)(125.0/192.0), B5c = (float)(-2187.0/6784.0),
                B6c = (float)(11.0/84.0);
constexpr float E1c = (float)(71.0/57600.0), E3c = (float)(-71.0/16695.0),
                E4c = (float)(71.0/1920.0), E5c = (float)(-17253.0/339200.0),
                E6c = (float)(22.0/525.0),  E7c = (float)(-1.0/40.0);
constexpr float RTOL = 1e-3f, ATOL = 1e-3f;

// ws layout (floats / ints)
constexpr size_t OFF_PART = 0;        // 1024 floats (double-buffered by step parity)
constexpr size_t OFF_FLAG = 1024;     // 512 ints
constexpr size_t OFF_CNT  = 1536;     // 1 int (+pad)
constexpr size_t OFF_TSUM = 1600;     // 576
constexpr size_t OFF_W2P  = 2176;     // 73728 ushorts = 36864 floats
constexpr size_t OFF_Y    = 39040;
constexpr size_t OFF_Y5   = OFF_Y  + (size_t)NS;
constexpr size_t OFF_K    = OFF_Y5 + (size_t)NS;   // 7*NS (k1..k7 slots)
}

__constant__ float g_cf[6][5] = {
    {A21, 0, 0, 0, 0},
    {A31, A32, 0, 0, 0},
    {A41, A42, A43, 0, 0},
    {A51, A52, A53, A54, 0},
    {A61, A62, A63, A64, A65},
    {0, 0, 0, 0, 0}};
__constant__ float g_ct[6] = {C2f, C3f, C4f, C5f, 1.0f, 1.0f};

typedef __bf16 bfrag8 __attribute__((ext_vector_type(8)));
typedef float f32x4 __attribute__((ext_vector_type(4)));

__device__ __forceinline__ unsigned short f2bf(float f) {
    unsigned u = __float_as_uint(f);
    unsigned r = u + 0x7fffu + ((u >> 16) & 1u);
    return (unsigned short)(r >> 16);
}
__device__ __forceinline__ float bf2f(unsigned short h) {
    return __uint_as_float(((unsigned)h) << 16);
}

// ---- system-scope (L3-coherent) accessors: bypass L1/L2, no cache maintenance ----
__device__ __forceinline__ float ld_sysf(const float* p) {
    return __hip_atomic_load(p, __ATOMIC_RELAXED, __HIP_MEMORY_SCOPE_SYSTEM);
}
__device__ __forceinline__ float2 ld_sysf2(const float* p) {
    union { unsigned long long u; float2 f; } c;
    c.u = __hip_atomic_load((const unsigned long long*)p, __ATOMIC_RELAXED,
                            __HIP_MEMORY_SCOPE_SYSTEM);
    return c.f;
}
__device__ __forceinline__ void st_sysf(float* p, float v) {
    __hip_atomic_store(p, v, __ATOMIC_RELAXED, __HIP_MEMORY_SCOPE_SYSTEM);
}
__device__ __forceinline__ void st_sysf2(float* p, float a, float b) {
    union { unsigned long long u; float2 f; } c;
    c.f = make_float2(a, b);
    __hip_atomic_store((unsigned long long*)p, c.u, __ATOMIC_RELAXED,
                       __HIP_MEMORY_SCOPE_SYSTEM);
}

// ---------------- init: y0 = concat(x, zeros); zero sync state ----------------
__global__ __launch_bounds__(256)
void k_init(const float* __restrict__ x, float* __restrict__ y,
            int* __restrict__ flags, unsigned* __restrict__ cnt)
{
    int idx = blockIdx.x*256 + threadIdx.x;
    int b = idx >> 13, c = (idx >> 10) & 7, p = idx & 1023;
    y[idx] = (c < 3) ? x[(size_t)(b*3 + c)*1024 + p] : 0.0f;
    if (idx < 512) flags[idx] = 0;
    if (idx == 600) *cnt = 0u;
}

// ---------------- prepack w2 into MFMA B-frag order + t-channel mask table ----------------
__global__ __launch_bounds__(256)
void k_prepack(const float* __restrict__ w2, unsigned short* __restrict__ w2p,
               float* __restrict__ tsum)
{
    int gid = blockIdx.x*256 + threadIdx.x;
    if (gid < 73728) {
        int j    = gid & 7;
        int lane = (gid >> 3) & 63;
        int nt   = (gid >> 9) & 3;
        int r    = gid >> 11;            // (part*2+cc)*9 + tap
        int tap  = r % 9;
        int pc   = r / 9;
        int cc   = pc & 1, part = pc >> 1;
        int oc = nt*16 + (lane & 15);
        int ic = cc*32 + (lane >> 4)*8 + j;
        float wv = w2[oc*585 + (1 + ic)*9 + tap];
        unsigned short hi = f2bf(wv);
        w2p[gid] = (part == 0) ? hi : f2bf(wv - bf2f(hi));
    }
    if (gid < 576) {
        int oc = gid & 63, combo = gid >> 6;       // 0..8
        int rcase = combo / 3, ccase = combo % 3;
        float s = 0.0f;
        for (int kh = 0; kh < 3; kh++) {
            if ((rcase == 1 && kh == 0) || (rcase == 2 && kh == 2)) continue;
            for (int kw = 0; kw < 3; kw++) {
                if ((ccase == 1 && kw == 0) || (ccase == 2 && kw == 2)) continue;
                s += w2[oc*585 + kh*3 + kw];
            }
        }
        tsum[gid] = s;
    }
}

// ---------------- the whole ODE solve: one co-resident kernel, NO grid.sync ----------------
// All k/y tensor I/O is system-scope (L3-coherent). Neighbor halo dep enforced by
// per-tile monotonic flags; one counter rendezvous per step for err-norm control.
__global__ void __launch_bounds__(256, 2)
k_ode(const float* __restrict__ w1, const float* __restrict__ b1,
      const float* __restrict__ b2, const float* __restrict__ w3,
      const float* __restrict__ b3, const unsigned short* __restrict__ w2p,
      const float* __restrict__ tsumg, const float* __restrict__ wl,
      const float* __restrict__ bl, float* __restrict__ ybuf,
      float* __restrict__ y5buf, float* __restrict__ kb,
      float* __restrict__ part, int* __restrict__ flags,
      unsigned* __restrict__ cnt, float* __restrict__ out)
{
    __shared__ __align__(16) unsigned char s_pool[55488];
    __shared__ __align__(16) float s_w1t[8][64];
    __shared__ float s_w10[64], s_b1v[64];
    __shared__ __align__(16) float s_w3t[64][8];
    __shared__ float s_w30[8], s_b3v[8];
    __shared__ float s_tsum[576];
    __shared__ float s_b2v[64];
    __shared__ float s_red[256];

    const int tid = threadIdx.x;
    const int nblk = gridDim.x;
    const int lane = tid & 63, l15 = lane & 15, q = lane >> 4;
    const int rp = tid >> 7;          // row-pair of the 4-row tile
    const int np = (tid >> 6) & 1;    // oc-pair

    if (tid < 64) {
        s_b1v[tid] = b1[tid];
        s_w10[tid] = w1[tid*9];
        #pragma unroll
        for (int c = 0; c < 8; c++) s_w1t[c][tid] = w1[tid*9 + 1 + c];
        s_b2v[tid] = b2[tid];
        #pragma unroll
        for (int o = 0; o < 8; o++) s_w3t[tid][o] = w3[o*65 + 1 + tid];
        if (tid < 8) { s_w30[tid] = w3[tid*65]; s_b3v[tid] = b3[tid]; }
    }
    for (int i = tid; i < 576; i += 256) s_tsum[i] = tsumg[i];

    float t = 0.0f, dt = 0.1f;
    float* ya = ybuf; float* yb = y5buf;
    float* ka = kb;  float* kg = kb + 6*(size_t)NS;

    auto eval = [&](const float* src, int nc, const float* cf, float ctv,
                    float* kout, int mode, int gev, float* partp) {
        float dtc = fminf(dt, 1.0f - t);
        float ts  = t + ctv*dtc;

        for (int tile = blockIdx.x; tile < 512; tile += nblk) {
            int b = tile >> 3, rg = tile & 7;

            // 1) zero activation pool; tid0 concurrently spins on neighbor flags
            {
                uint4 z4 = make_uint4(0u,0u,0u,0u);
                uint4* p4 = (uint4*)s_pool;
                for (int i = tid; i < 3468; i += 256) p4[i] = z4;
            }
            if (tid == 0 && gev > 1) {
                if (rg > 0)
                    while (__hip_atomic_load(&flags[tile-1], __ATOMIC_RELAXED,
                                             __HIP_MEMORY_SCOPE_SYSTEM) < gev-1)
                        __builtin_amdgcn_s_sleep(1);
                if (rg < 7)
                    while (__hip_atomic_load(&flags[tile+1], __ATOMIC_RELAXED,
                                             __HIP_MEMORY_SCOPE_SYSTEM) < gev-1)
                        __builtin_amdgcn_s_sleep(1);
            }
            __syncthreads();

            // 2) conv1 (z-combine + 1x1 9->64 + relu) into LDS, 6 rows incl halo
            if (tid < 192) {
                int lr = tid >> 5, col = tid & 31;
                int r = rg*4 - 1 + lr;
                if ((unsigned)r < 32u) {
                    int px = (r << 5) + col;
                    float s[8] = {0,0,0,0,0,0,0,0};
                    for (int j = 0; j < nc; j++) {
                        const float* kp = (j == 0 ? ka : kb + (size_t)j*NS)
                                          + (((size_t)(b << 10) + px) << 3);
                        float a = cf[j];
                        #pragma unroll
                        for (int h = 0; h < 4; h++) {
                            float2 kv = ld_sysf2(kp + 2*h);
                            s[2*h]   += a*kv.x;
                            s[2*h+1] += a*kv.y;
                        }
                    }
                    float zz[8];
                    #pragma unroll
                    for (int c = 0; c < 8; c++)
                        zz[c] = ld_sysf(src + ((b*8 + c) << 10) + px) + dtc*s[c];
                    float acc[64];
                    #pragma unroll
                    for (int o = 0; o < 64; o++) acc[o] = fmaf(ts, s_w10[o], s_b1v[o]);
                    #pragma unroll
                    for (int c = 0; c < 8; c++) {
                        float zc = zz[c];
                        const float4* w4 = reinterpret_cast<const float4*>(&s_w1t[c][0]);
                        #pragma unroll
                        for (int qq = 0; qq < 16; qq++) {
                            float4 wq = w4[qq];
                            acc[4*qq+0] = fmaf(wq.x, zc, acc[4*qq+0]);
                            acc[4*qq+1] = fmaf(wq.y, zc, acc[4*qq+1]);
                            acc[4*qq+2] = fmaf(wq.z, zc, acc[4*qq+2]);
                            acc[4*qq+3] = fmaf(wq.w, zc, acc[4*qq+3]);
                        }
                    }
                    unsigned hibuf[32], lobuf[32];
                    #pragma unroll
                    for (int i = 0; i < 32; i++) {
                        float f0 = fmaxf(acc[2*i],   0.0f);
                        float f1 = fmaxf(acc[2*i+1], 0.0f);
                        unsigned short h0 = f2bf(f0), h1v = f2bf(f1);
                        unsigned short l0 = f2bf(f0 - bf2f(h0)), l1 = f2bf(f1 - bf2f(h1v));
                        hibuf[i] = (unsigned)h0 | ((unsigned)h1v << 16);
                        lobuf[i] = (unsigned)l0 | ((unsigned)l1 << 16);
                    }
                    int pxi = lr*34 + col + 1;
                    uint4* d = (uint4*)(s_pool + (size_t)pxi*272);
                    const uint4* hbv = (const uint4*)hibuf;
                    const uint4* lbv = (const uint4*)lobuf;
                    #pragma unroll
                    for (int i = 0; i < 8; i++) d[i] = hbv[i];
                    #pragma unroll
                    for (int i = 0; i < 8; i++) d[8 + i] = lbv[i];
                }
            }
            __syncthreads();

            // 3) conv2: 3x3 65->64 split-bf16 MFMA, quadrant split
            f32x4 acc2[2][2][2];   // [ri][ch][nn]
            #pragma unroll
            for (int ri = 0; ri < 2; ri++)
                #pragma unroll
                for (int ch = 0; ch < 2; ch++)
                    #pragma unroll
                    for (int nn = 0; nn < 2; nn++)
                        acc2[ri][ch][nn] = (f32x4){0.f,0.f,0.f,0.f};

            for (int cc = 0; cc < 2; cc++) {
                const unsigned short* wp_hi = w2p + (size_t)(cc*9)*2048;
                const unsigned short* wp_lo = w2p + (size_t)((2 + cc)*9)*2048;
                #pragma unroll 1
                for (int kh = 0; kh < 3; kh++) {
                    #pragma unroll
                    for (int kw = 0; kw < 3; kw++) {
                        int tap = kh*3 + kw;
                        bfrag8 bh[2], bl[2];
                        #pragma unroll
                        for (int nn = 0; nn < 2; nn++) {
                            int nt = np*2 + nn;
                            bh[nn] = *(const bfrag8*)(wp_hi + (size_t)(tap*4 + nt)*512 + lane*8);
                            bl[nn] = *(const bfrag8*)(wp_lo + (size_t)(tap*4 + nt)*512 + lane*8);
                        }
                        #pragma unroll
                        for (int ri = 0; ri < 2; ri++) {
                            int lr = rp*2 + ri + kh;
                            bfrag8 ah[2], al[2];
                            #pragma unroll
                            for (int ch = 0; ch < 2; ch++) {
                                int lc = ch*16 + l15 + kw;
                                const unsigned char* pxp = s_pool
                                    + (size_t)(lr*34 + lc)*272 + cc*64 + q*16;
                                ah[ch] = *(const bfrag8*)pxp;
                                al[ch] = *(const bfrag8*)(pxp + 128);
                            }
                            #pragma unroll
                            for (int ch = 0; ch < 2; ch++)
                                #pragma unroll
                                for (int nn = 0; nn < 2; nn++)
                                    acc2[ri][ch][nn] = __builtin_amdgcn_mfma_f32_16x16x32_bf16(
                                        ah[ch], bh[nn], acc2[ri][ch][nn], 0, 0, 0);
                            #pragma unroll
                            for (int ch = 0; ch < 2; ch++)
                                #pragma unroll
                                for (int nn = 0; nn < 2; nn++)
                                    acc2[ri][ch][nn] = __builtin_amdgcn_mfma_f32_16x16x32_bf16(
                                        ah[ch], bl[nn], acc2[ri][ch][nn], 0, 0, 0);
                            #pragma unroll
                            for (int ch = 0; ch < 2; ch++)
                                #pragma unroll
                                for (int nn = 0; nn < 2; nn++)
                                    acc2[ri][ch][nn] = __builtin_amdgcn_mfma_f32_16x16x32_bf16(
                                        al[ch], bh[nn], acc2[ri][ch][nn], 0, 0, 0);
                        }
                    }
                }
            }
            __syncthreads();   // before h2 overlay on pool

            // 4) epilogue: t-channel + bias + relu -> LDS h2, oc-major stride 129
            {
                float* s_h2 = (float*)s_pool;
                #pragma unroll
                for (int ri = 0; ri < 2; ri++) {
                    int lrow = rp*2 + ri;
                    int r_out = rg*4 + lrow;
                    int rcase = (r_out == 0) ? 1 : ((r_out == 31) ? 2 : 0);
                    #pragma unroll
                    for (int ch = 0; ch < 2; ch++) {
                        #pragma unroll
                        for (int reg = 0; reg < 4; reg++) {
                            int c = ch*16 + q*4 + reg;
                            int ccase = (c == 0) ? 1 : ((c == 31) ? 2 : 0);
                            const float* tsp = s_tsum + (rcase*3 + ccase)*64;
                            int pxl = lrow*32 + c;
                            #pragma unroll
                            for (int nn = 0; nn < 2; nn++) {
                                int oc = (np*2 + nn)*16 + l15;
                                s_h2[oc*129 + pxl] =
                                    fmaxf(acc2[ri][ch][nn][reg] + ts*tsp[oc] + s_b2v[oc], 0.0f);
                            }
                        }
                    }
                }
            }
            __syncthreads();

            // 5) conv3 (1x1 65->8) + mode epilogues (all global I/O system-scope)
            if (tid < 128) {
                const float* s_h2 = (const float*)s_pool;
                float a3[8];
                #pragma unroll
                for (int o = 0; o < 8; o++) a3[o] = fmaf(ts, s_w30[o], s_b3v[o]);
                #pragma unroll 8
                for (int c = 0; c < 64; c++) {
                    float xv = s_h2[c*129 + tid];
                    const float4* w4 = (const float4*)&s_w3t[c][0];
                    float4 wA = w4[0], wB = w4[1];
                    a3[0] = fmaf(wA.x, xv, a3[0]);
                    a3[1] = fmaf(wA.y, xv, a3[1]);
                    a3[2] = fmaf(wA.z, xv, a3[2]);
                    a3[3] = fmaf(wA.w, xv, a3[3]);
                    a3[4] = fmaf(wB.x, xv, a3[4]);
                    a3[5] = fmaf(wB.y, xv, a3[5]);
                    a3[6] = fmaf(wB.z, xv, a3[6]);
                    a3[7] = fmaf(wB.w, xv, a3[7]);
                }
                int px = rg*128 + tid;
                size_t pb8 = ((size_t)(b << 10) + px) << 3;
                st_sysf2(kout + pb8,     a3[0], a3[1]);
                st_sysf2(kout + pb8 + 2, a3[2], a3[3]);
                st_sysf2(kout + pb8 + 4, a3[4], a3[5]);
                st_sysf2(kout + pb8 + 6, a3[6], a3[7]);
                if (mode == 1) {
                    float kv[4][8];
                    const float* kp1 = ka + pb8;
                    const float* kp3 = kb + 2*(size_t)NS + pb8;
                    const float* kp4 = kb + 3*(size_t)NS + pb8;
                    const float* kp5 = kb + 4*(size_t)NS + pb8;
                    #pragma unroll
                    for (int h = 0; h < 4; h++) {
                        float2 v1 = ld_sysf2(kp1 + 2*h), v3 = ld_sysf2(kp3 + 2*h);
                        float2 v4 = ld_sysf2(kp4 + 2*h), v5 = ld_sysf2(kp5 + 2*h);
                        kv[0][2*h] = v1.x; kv[0][2*h+1] = v1.y;
                        kv[1][2*h] = v3.x; kv[1][2*h+1] = v3.y;
                        kv[2][2*h] = v4.x; kv[2][2*h+1] = v4.y;
                        kv[3][2*h] = v5.x; kv[3][2*h+1] = v5.y;
                    }
                    #pragma unroll
                    for (int c = 0; c < 8; c++) {
                        size_t id = ((size_t)(b*8 + c) << 10) + px;
                        float yv = ld_sysf(ya + id);
                        st_sysf(yb + id, yv + dtc*(B1c*kv[0][c] + B3c*kv[1][c]
                                        + B4c*kv[2][c] + B5c*kv[3][c] + B6c*a3[c]));
                    }
                } else if (mode == 2) {
                    float kv[5][8];
                    const float* kp1 = ka + pb8;
                    const float* kp3 = kb + 2*(size_t)NS + pb8;
                    const float* kp4 = kb + 3*(size_t)NS + pb8;
                    const float* kp5 = kb + 4*(size_t)NS + pb8;
                    const float* kp6 = kb + 5*(size_t)NS + pb8;
                    #pragma unroll
                    for (int h = 0; h < 4; h++) {
                        float2 v1 = ld_sysf2(kp1 + 2*h), v3 = ld_sysf2(kp3 + 2*h);
                        float2 v4 = ld_sysf2(kp4 + 2*h), v5 = ld_sysf2(kp5 + 2*h);
                        float2 v6 = ld_sysf2(kp6 + 2*h);
                        kv[0][2*h] = v1.x; kv[0][2*h+1] = v1.y;
                        kv[1][2*h] = v3.x; kv[1][2*h+1] = v3.y;
                        kv[2][2*h] = v4.x; kv[2][2*h+1] = v4.y;
                        kv[3][2*h] = v5.x; kv[3][2*h+1] = v5.y;
                        kv[4][2*h] = v6.x; kv[4][2*h+1] = v6.y;
                    }
                    float ls = 0.0f;
                    #pragma unroll
                    for (int c = 0; c < 8; c++) {
                        size_t id = ((size_t)(b*8 + c) << 10) + px;
                        float e = dtc*(E1c*kv[0][c] + E3c*kv[1][c] + E4c*kv[2][c]
                                       + E5c*kv[3][c] + E6c*kv[4][c] + E7c*a3[c]);
                        float tol = ATOL + RTOL*fmaxf(fabsf(ld_sysf(ya + id)),
                                                      fabsf(ld_sysf(yb + id)));
                        float rr = e / tol;
                        ls += rr*rr;
                    }
                    s_red[tid] = ls;
                }
            }
            if (mode == 2) {
                if (tid >= 128) s_red[tid] = 0.0f;
                __syncthreads();
                for (int sft = 128; sft > 0; sft >>= 1) {
                    if (tid < sft) s_red[tid] += s_red[tid + sft];
                    __syncthreads();
                }
                if (tid == 0) st_sysf(&partp[tile], s_red[0]);
            }
            // release: __syncthreads drains each wave's vmcnt before s_barrier,
            // so all system-scope stores are L3-visible; then publish the flag.
            __syncthreads();
            if (tid == 0)
                __hip_atomic_store(&flags[tile], gev, __ATOMIC_RELAXED,
                                   __HIP_MEMORY_SCOPE_SYSTEM);
        }
    };

    int gev = 1;
    eval(ya, 0, g_cf[5], 0.0f, ka, 0, gev, part);   // k1 = f(t0, y0)
    gev++;

    for (int st = 0; st < 24; st++) {
        if (t >= 1.0f - 1e-7f) break;
        float* partp = part + (size_t)(st & 1)*512;
        for (int e = 0; e < 6; e++) {
            int nc = (e < 5) ? e + 1 : 0;
            const float* src = (e == 5) ? yb : ya;
            float* kout = (e < 5) ? kb + (size_t)(e + 1)*NS : kg;
            int mode = (e == 4) ? 1 : ((e == 5) ? 2 : 0);
            eval(src, nc, g_cf[e], g_ct[e], kout, mode, gev, partp);
            gev++;
        }
        // per-step rendezvous: counter at system scope, then deterministic reduce
        __syncthreads();
        if (tid == 0) {
            __hip_atomic_fetch_add(cnt, 1u, __ATOMIC_RELAXED, __HIP_MEMORY_SCOPE_SYSTEM);
            unsigned target = (unsigned)nblk * (unsigned)(st + 1);
            while (__hip_atomic_load(cnt, __ATOMIC_RELAXED,
                                     __HIP_MEMORY_SCOPE_SYSTEM) < target)
                __builtin_amdgcn_s_sleep(2);
        }
        __syncthreads();
        float v = ld_sysf(&partp[tid]) + ld_sysf(&partp[tid + 256]);
        s_red[tid] = v;
        __syncthreads();
        for (int sft = 128; sft > 0; sft >>= 1) {
            if (tid < sft) s_red[tid] += s_red[tid + sft];
            __syncthreads();
        }
        float red0 = s_red[0];
        __syncthreads();
        float err_norm = sqrtf(red0 / (float)NS);
        float dtc = fminf(dt, 1.0f - t);
        bool adv = (err_norm <= 1.0f);
        if (adv) {
            t = t + dtc;
            float* tmp = ya; ya = yb; yb = tmp;   // y <- y5
            tmp = ka; ka = kg; kg = tmp;          // k1 <- k7 (FSAL)
        }
        float safe = fmaxf(err_norm, 1e-10f);
        float factor = fminf(fmaxf(0.9f*powf(safe, -0.2f), 0.2f), 10.0f);
        dt = dtc*factor;
    }

    // final linear head (ya fully visible at system scope after last rendezvous)
    __syncthreads();
    for (int bh = blockIdx.x; bh < 64; bh += nblk) {
        float* s_hred = (float*)s_pool;   // 10*256 floats overlay
        float acc[10];
        #pragma unroll
        for (int m = 0; m < 10; m++) acc[m] = 0.0f;
        for (int f = tid; f < 8192; f += 256) {
            float yv = ld_sysf(ya + (size_t)bh*8192 + f);
            #pragma unroll
            for (int m = 0; m < 10; m++) acc[m] = fmaf(yv, wl[(size_t)m*8192 + f], acc[m]);
        }
        #pragma unroll
        for (int m = 0; m < 10; m++) s_hred[m*256 + tid] = acc[m];
        __syncthreads();
        for (int sft = 128; sft > 0; sft >>= 1) {
            if (tid < sft) {
                #pragma unroll
                for (int m = 0; m < 10; m++)
                    s_hred[m*256 + tid] += s_hred[m*256 + tid + sft];
            }
            __syncthreads();
        }
        if (tid < 10) out[bh*10 + tid] = s_hred[tid*256] + bl[tid];
        __syncthreads();
    }
}

// ---------------- host ----------------
extern "C" void kernel_launch(void* const* d_in, const int* in_sizes, int n_in,
                              void* d_out, int out_size, void* d_ws, size_t ws_size,
                              hipStream_t stream)
{
    const float* x  = (const float*)d_in[0];
    const float* w1 = (const float*)d_in[1];
    const float* b1 = (const float*)d_in[2];
    const float* w2 = (const float*)d_in[3];
    const float* b2 = (const float*)d_in[4];
    const float* w3 = (const float*)d_in[5];
    const float* b3 = (const float*)d_in[6];
    const float* wl = (const float*)d_in[7];
    const float* bl = (const float*)d_in[8];
    float* out = (float*)d_out;

    float* F = (float*)d_ws;
    float* part = F + OFF_PART;
    int*   flags = (int*)(F + OFF_FLAG);
    unsigned* cnt = (unsigned*)(F + OFF_CNT);
    float* tsum = F + OFF_TSUM;
    unsigned short* w2p = (unsigned short*)(F + OFF_W2P);
    float* y    = F + OFF_Y;
    float* y5   = F + OFF_Y5;
    float* kbp  = F + OFF_K;

    k_init<<<NS/256, 256, 0, stream>>>(x, y, flags, cnt);
    k_prepack<<<288, 256, 0, stream>>>(w2, w2p, tsum);

    // co-resident grid (cooperative launch for the residency guarantee)
    int maxb = 0;
    if (hipOccupancyMaxActiveBlocksPerMultiprocessor(&maxb,
            reinterpret_cast<const void*>(k_ode), 256, 0) != hipSuccess || maxb < 1)
        maxb = 1;
    int cus = 256;
    {
        int dev = 0;
        hipGetDevice(&dev);
        hipDeviceProp_t prop;
        if (hipGetDeviceProperties(&prop, dev) == hipSuccess && prop.multiProcessorCount > 0)
            cus = prop.multiProcessorCount;
    }
    long cap = (long)maxb * (long)cus;
    int gridn = (int)((cap < 512) ? cap : 512);
    if (gridn < 16) gridn = 16;

    void* args[] = {
        (void*)&w1, (void*)&b1, (void*)&b2, (void*)&w3, (void*)&b3,
        (void*)&w2p, (void*)&tsum, (void*)&wl, (void*)&bl,
        (void*)&y, (void*)&y5, (void*)&kbp, (void*)&part,
        (void*)&flags, (void*)&cnt, (void*)&out
    };
    hipLaunchCooperativeKernel((void*)k_ode, dim3(gridn), dim3(256), args, 0, stream);
}

// Round 8
// 755.148 us; speedup vs baseline: 2.2306x; 1.0181x over previous
//
#include <hip/hip_runtime.h>
#include <math.h>

namespace {
constexpr int BN = 64;
constexpr int HW = 1024;
constexpr int NS = BN*8*HW;      // 524288

constexpr float C2f = 0.2f, C3f = 0.3f, C4f = 0.8f, C5f = (float)(8.0/9.0);
constexpr float A21 = 0.2f;
constexpr float A31 = (float)(3.0/40.0),  A32 = (float)(9.0/40.0);
constexpr float A41 = (float)(44.0/45.0), A42 = (float)(-56.0/15.0), A43 = (float)(32.0/9.0);
constexpr float A51 = (float)(19372.0/6561.0), A52 = (float)(-25360.0/2187.0),
                A53 = (float)(64448.0/6561.0), A54 = (float)(-212.0/729.0);
constexpr float A61 = (float)(9017.0/3168.0), A62 = (float)(-355.0/33.0),
                A63 = (float)(46732.0/5247.0), A64 = (float)(49.0/176.0),
                A65 = (float)(-5103.0/18656.0);
constexpr float B1c = (float)(35.0/384.0), B3c = (float)(500.0/1113.0),
                B4c = (float)(125.0/192.0), B5c = (float)(-2187.0/6784.0),
                B6c = (float)(11.0/84.0);
constexpr float E1c = (float)(71.0/57600.0), E3c = (float)(-71.0/16695.0),
                E4c = (float)(71.0/1920.0), E5c = (float)(-17253.0/339200.0),
                E6c = (float)(22.0/525.0),  E7c = (float)(-1.0/40.0);
constexpr float RTOL = 1e-3f, ATOL = 1e-3f;

// ws layout (floats / ints)
constexpr size_t OFF_PART = 0;        // 1024 floats (double-buffered by step parity)
constexpr size_t OFF_FLAG = 1024;     // 512 ints
constexpr size_t OFF_CNT  = 1536;     // 1 int (+pad)
constexpr size_t OFF_TSUM = 1600;     // 576
constexpr size_t OFF_W2P  = 2176;     // 73728 ushorts = 36864 floats
constexpr size_t OFF_Y    = 39040;    // y buffers now px-major: [b][px][8]
constexpr size_t OFF_Y5   = OFF_Y  + (size_t)NS;
constexpr size_t OFF_K    = OFF_Y5 + (size_t)NS;   // 7*NS (k1..k7 slots, px-major)
}

__constant__ float g_cf[6][5] = {
    {A21, 0, 0, 0, 0},
    {A31, A32, 0, 0, 0},
    {A41, A42, A43, 0, 0},
    {A51, A52, A53, A54, 0},
    {A61, A62, A63, A64, A65},
    {0, 0, 0, 0, 0}};
__constant__ float g_ct[6] = {C2f, C3f, C4f, C5f, 1.0f, 1.0f};

typedef __bf16 bfrag8 __attribute__((ext_vector_type(8)));
typedef float f32x4 __attribute__((ext_vector_type(4)));

__device__ __forceinline__ unsigned short f2bf(float f) {
    unsigned u = __float_as_uint(f);
    unsigned r = u + 0x7fffu + ((u >> 16) & 1u);
    return (unsigned short)(r >> 16);
}
__device__ __forceinline__ float bf2f(unsigned short h) {
    return __uint_as_float(((unsigned)h) << 16);
}

// ---- system-scope (L3-coherent) accessors ----
__device__ __forceinline__ float ld_sysf(const float* p) {
    return __hip_atomic_load(p, __ATOMIC_RELAXED, __HIP_MEMORY_SCOPE_SYSTEM);
}
__device__ __forceinline__ float2 ld_sysf2(const float* p) {
    union { unsigned long long u; float2 f; } c;
    c.u = __hip_atomic_load((const unsigned long long*)p, __ATOMIC_RELAXED,
                            __HIP_MEMORY_SCOPE_SYSTEM);
    return c.f;
}
__device__ __forceinline__ void st_sysf(float* p, float v) {
    __hip_atomic_store(p, v, __ATOMIC_RELAXED, __HIP_MEMORY_SCOPE_SYSTEM);
}
__device__ __forceinline__ void st_sysf2(float* p, float a, float b) {
    union { unsigned long long u; float2 f; } c;
    c.f = make_float2(a, b);
    __hip_atomic_store((unsigned long long*)p, c.u, __ATOMIC_RELAXED,
                       __HIP_MEMORY_SCOPE_SYSTEM);
}

// 8-float load/store with scope selected by row class (sys = boundary row)
__device__ __forceinline__ void ld8(const float* p, float* v, bool sys) {
    if (sys) {
        #pragma unroll
        for (int h = 0; h < 4; h++) {
            float2 t = ld_sysf2(p + 2*h);
            v[2*h] = t.x; v[2*h+1] = t.y;
        }
    } else {
        float4 a = *(const float4*)p;
        float4 b = *(const float4*)(p + 4);
        v[0]=a.x; v[1]=a.y; v[2]=a.z; v[3]=a.w;
        v[4]=b.x; v[5]=b.y; v[6]=b.z; v[7]=b.w;
    }
}
__device__ __forceinline__ void st8(float* p, const float* v, bool sys) {
    if (sys) {
        st_sysf2(p,     v[0], v[1]);
        st_sysf2(p + 2, v[2], v[3]);
        st_sysf2(p + 4, v[4], v[5]);
        st_sysf2(p + 6, v[6], v[7]);
    } else {
        *(float4*)p       = make_float4(v[0], v[1], v[2], v[3]);
        *(float4*)(p + 4) = make_float4(v[4], v[5], v[6], v[7]);
    }
}

// ---------------- init: y0 (px-major) = concat(x, zeros); zero sync state ----------------
__global__ __launch_bounds__(256)
void k_init(const float* __restrict__ x, float* __restrict__ y,
            int* __restrict__ flags, unsigned* __restrict__ cnt)
{
    int idx = blockIdx.x*256 + threadIdx.x;           // < NS
    int b = idx >> 13, px = (idx >> 3) & 1023, c = idx & 7;
    y[idx] = (c < 3) ? x[(size_t)(b*3 + c)*1024 + px] : 0.0f;
    if (idx < 512) flags[idx] = 0;
    if (idx == 600) *cnt = 0u;
}

// ---------------- prepack w2 into MFMA B-frag order + t-channel mask table ----------------
__global__ __launch_bounds__(256)
void k_prepack(const float* __restrict__ w2, unsigned short* __restrict__ w2p,
               float* __restrict__ tsum)
{
    int gid = blockIdx.x*256 + threadIdx.x;
    if (gid < 73728) {
        int j    = gid & 7;
        int lane = (gid >> 3) & 63;
        int nt   = (gid >> 9) & 3;
        int r    = gid >> 11;            // (part*2+cc)*9 + tap
        int tap  = r % 9;
        int pc   = r / 9;
        int cc   = pc & 1, part = pc >> 1;
        int oc = nt*16 + (lane & 15);
        int ic = cc*32 + (lane >> 4)*8 + j;
        float wv = w2[oc*585 + (1 + ic)*9 + tap];
        unsigned short hi = f2bf(wv);
        w2p[gid] = (part == 0) ? hi : f2bf(wv - bf2f(hi));
    }
    if (gid < 576) {
        int oc = gid & 63, combo = gid >> 6;       // 0..8
        int rcase = combo / 3, ccase = combo % 3;
        float s = 0.0f;
        for (int kh = 0; kh < 3; kh++) {
            if ((rcase == 1 && kh == 0) || (rcase == 2 && kh == 2)) continue;
            for (int kw = 0; kw < 3; kw++) {
                if ((ccase == 1 && kw == 0) || (ccase == 2 && kw == 2)) continue;
                s += w2[oc*585 + kh*3 + kw];
            }
        }
        tsum[gid] = s;
    }
}

// ---------------- the whole ODE solve: one co-resident kernel ----------------
// Scope-split: tile boundary rows (0,3) -> system-scope everywhere (cross-block
// halo); interior rows (1,2) -> normal cached access (block-private). Final y
// interior rows are flushed to L3 once before the head.
__global__ void __launch_bounds__(256, 2)
k_ode(const float* __restrict__ w1, const float* __restrict__ b1,
      const float* __restrict__ b2, const float* __restrict__ w3,
      const float* __restrict__ b3, const unsigned short* __restrict__ w2p,
      const float* __restrict__ tsumg, const float* __restrict__ wl,
      const float* __restrict__ bl, float* __restrict__ ybuf,
      float* __restrict__ y5buf, float* __restrict__ kb,
      float* __restrict__ part, int* __restrict__ flags,
      unsigned* __restrict__ cnt, float* __restrict__ out)
{
    __shared__ __align__(16) unsigned char s_pool[55488];
    __shared__ __align__(16) float s_w1t[8][64];
    __shared__ float s_w10[64], s_b1v[64];
    __shared__ __align__(16) float s_w3t[64][8];
    __shared__ float s_w30[8], s_b3v[8];
    __shared__ float s_tsum[576];
    __shared__ float s_b2v[64];
    __shared__ float s_red[256];

    const int tid = threadIdx.x;
    const int nblk = gridDim.x;
    const int lane = tid & 63, l15 = lane & 15, q = lane >> 4;
    const int rp = tid >> 7;          // row-pair of the 4-row tile
    const int np = (tid >> 6) & 1;    // oc-pair

    if (tid < 64) {
        s_b1v[tid] = b1[tid];
        s_w10[tid] = w1[tid*9];
        #pragma unroll
        for (int c = 0; c < 8; c++) s_w1t[c][tid] = w1[tid*9 + 1 + c];
        s_b2v[tid] = b2[tid];
        #pragma unroll
        for (int o = 0; o < 8; o++) s_w3t[tid][o] = w3[o*65 + 1 + tid];
        if (tid < 8) { s_w30[tid] = w3[tid*65]; s_b3v[tid] = b3[tid]; }
    }
    for (int i = tid; i < 576; i += 256) s_tsum[i] = tsumg[i];

    float t = 0.0f, dt = 0.1f;
    float* ya = ybuf; float* yb = y5buf;
    float* ka = kb;  float* kg = kb + 6*(size_t)NS;
    unsigned rnd = 0;

    auto rendezvous = [&]() {
        rnd++;
        __syncthreads();   // drains each wave's outstanding stores (vmcnt) first
        if (tid == 0) {
            __hip_atomic_fetch_add(cnt, 1u, __ATOMIC_RELAXED, __HIP_MEMORY_SCOPE_SYSTEM);
            unsigned target = (unsigned)nblk * rnd;
            while (__hip_atomic_load(cnt, __ATOMIC_RELAXED,
                                     __HIP_MEMORY_SCOPE_SYSTEM) < target)
                __builtin_amdgcn_s_sleep(2);
        }
        __syncthreads();
    };

    auto eval = [&](const float* src, int nc, const float* cf, float ctv,
                    float* kout, int mode, int gev, float* partp) {
        float dtc = fminf(dt, 1.0f - t);
        float ts  = t + ctv*dtc;

        for (int tile = blockIdx.x; tile < 512; tile += nblk) {
            int b = tile >> 3, rg = tile & 7;

            // 1) zero halo columns (cols 0 & 33, 6 rows = 12 px); tid0 spins on flags
            if (tid < 192) {
                int px_id = tid >> 4, u = tid & 15;
                int row = px_id >> 1, colh = (px_id & 1) ? 33 : 0;
                *(uint4*)(s_pool + (size_t)(row*34 + colh)*272 + u*16) =
                    make_uint4(0u,0u,0u,0u);
            }
            if (tid == 0 && gev > 1) {
                if (rg > 0)
                    while (__hip_atomic_load(&flags[tile-1], __ATOMIC_RELAXED,
                                             __HIP_MEMORY_SCOPE_SYSTEM) < gev-1)
                        __builtin_amdgcn_s_sleep(1);
                if (rg < 7)
                    while (__hip_atomic_load(&flags[tile+1], __ATOMIC_RELAXED,
                                             __HIP_MEMORY_SCOPE_SYSTEM) < gev-1)
                        __builtin_amdgcn_s_sleep(1);
            }
            __syncthreads();

            // 2) conv1 (z-combine + 1x1 9->64 + relu) into LDS, 6 rows incl halo
            if (tid < 192) {
                int lr = tid >> 5, col = tid & 31;
                int r = rg*4 - 1 + lr;
                bool sysrow = (lr < 2) | (lr > 3);   // rows 1,2 of own tile are private
                int pxi = lr*34 + col + 1;
                uint4* d = (uint4*)(s_pool + (size_t)pxi*272);
                if ((unsigned)r < 32u) {
                    int px = (r << 5) + col;
                    size_t pb8 = ((size_t)(b << 10) + px) << 3;
                    float s[8] = {0,0,0,0,0,0,0,0};
                    for (int j = 0; j < nc; j++) {
                        const float* kp = (j == 0 ? ka : kb + (size_t)j*NS) + pb8;
                        float a = cf[j];
                        float kv[8];
                        ld8(kp, kv, sysrow);
                        #pragma unroll
                        for (int c = 0; c < 8; c++) s[c] += a*kv[c];
                    }
                    float zz[8];
                    {
                        float sv[8];
                        ld8(src + pb8, sv, sysrow);
                        #pragma unroll
                        for (int c = 0; c < 8; c++) zz[c] = sv[c] + dtc*s[c];
                    }
                    float acc[64];
                    #pragma unroll
                    for (int o = 0; o < 64; o++) acc[o] = fmaf(ts, s_w10[o], s_b1v[o]);
                    #pragma unroll
                    for (int c = 0; c < 8; c++) {
                        float zc = zz[c];
                        const float4* w4 = reinterpret_cast<const float4*>(&s_w1t[c][0]);
                        #pragma unroll
                        for (int qq = 0; qq < 16; qq++) {
                            float4 wq = w4[qq];
                            acc[4*qq+0] = fmaf(wq.x, zc, acc[4*qq+0]);
                            acc[4*qq+1] = fmaf(wq.y, zc, acc[4*qq+1]);
                            acc[4*qq+2] = fmaf(wq.z, zc, acc[4*qq+2]);
                            acc[4*qq+3] = fmaf(wq.w, zc, acc[4*qq+3]);
                        }
                    }
                    unsigned hibuf[32], lobuf[32];
                    #pragma unroll
                    for (int i = 0; i < 32; i++) {
                        float f0 = fmaxf(acc[2*i],   0.0f);
                        float f1 = fmaxf(acc[2*i+1], 0.0f);
                        unsigned short h0 = f2bf(f0), h1v = f2bf(f1);
                        unsigned short l0 = f2bf(f0 - bf2f(h0)), l1 = f2bf(f1 - bf2f(h1v));
                        hibuf[i] = (unsigned)h0 | ((unsigned)h1v << 16);
                        lobuf[i] = (unsigned)l0 | ((unsigned)l1 << 16);
                    }
                    const uint4* hbv = (const uint4*)hibuf;
                    const uint4* lbv = (const uint4*)lobuf;
                    #pragma unroll
                    for (int i = 0; i < 8; i++) d[i] = hbv[i];
                    #pragma unroll
                    for (int i = 0; i < 8; i++) d[8 + i] = lbv[i];
                } else {
                    uint4 z4 = make_uint4(0u,0u,0u,0u);
                    #pragma unroll
                    for (int i = 0; i < 16; i++) d[i] = z4;
                }
            }
            __syncthreads();

            // 3) conv2: 3x3 65->64 split-bf16 MFMA, quadrant split
            f32x4 acc2[2][2][2];   // [ri][ch][nn]
            #pragma unroll
            for (int ri = 0; ri < 2; ri++)
                #pragma unroll
                for (int ch = 0; ch < 2; ch++)
                    #pragma unroll
                    for (int nn = 0; nn < 2; nn++)
                        acc2[ri][ch][nn] = (f32x4){0.f,0.f,0.f,0.f};

            for (int cc = 0; cc < 2; cc++) {
                const unsigned short* wp_hi = w2p + (size_t)(cc*9)*2048;
                const unsigned short* wp_lo = w2p + (size_t)((2 + cc)*9)*2048;
                #pragma unroll 1
                for (int kh = 0; kh < 3; kh++) {
                    #pragma unroll
                    for (int kw = 0; kw < 3; kw++) {
                        int tap = kh*3 + kw;
                        bfrag8 bh[2], bl[2];
                        #pragma unroll
                        for (int nn = 0; nn < 2; nn++) {
                            int nt = np*2 + nn;
                            bh[nn] = *(const bfrag8*)(wp_hi + (size_t)(tap*4 + nt)*512 + lane*8);
                            bl[nn] = *(const bfrag8*)(wp_lo + (size_t)(tap*4 + nt)*512 + lane*8);
                        }
                        #pragma unroll
                        for (int ri = 0; ri < 2; ri++) {
                            int lr = rp*2 + ri + kh;
                            bfrag8 ah[2], al[2];
                            #pragma unroll
                            for (int ch = 0; ch < 2; ch++) {
                                int lc = ch*16 + l15 + kw;
                                const unsigned char* pxp = s_pool
                                    + (size_t)(lr*34 + lc)*272 + cc*64 + q*16;
                                ah[ch] = *(const bfrag8*)pxp;
                                al[ch] = *(const bfrag8*)(pxp + 128);
                            }
                            #pragma unroll
                            for (int ch = 0; ch < 2; ch++)
                                #pragma unroll
                                for (int nn = 0; nn < 2; nn++)
                                    acc2[ri][ch][nn] = __builtin_amdgcn_mfma_f32_16x16x32_bf16(
                                        ah[ch], bh[nn], acc2[ri][ch][nn], 0, 0, 0);
                            #pragma unroll
                            for (int ch = 0; ch < 2; ch++)
                                #pragma unroll
                                for (int nn = 0; nn < 2; nn++)
                                    acc2[ri][ch][nn] = __builtin_amdgcn_mfma_f32_16x16x32_bf16(
                                        ah[ch], bl[nn], acc2[ri][ch][nn], 0, 0, 0);
                            #pragma unroll
                            for (int ch = 0; ch < 2; ch++)
                                #pragma unroll
                                for (int nn = 0; nn < 2; nn++)
                                    acc2[ri][ch][nn] = __builtin_amdgcn_mfma_f32_16x16x32_bf16(
                                        al[ch], bh[nn], acc2[ri][ch][nn], 0, 0, 0);
                        }
                    }
                }
            }
            __syncthreads();   // before h2 overlay on pool

            // 4) epilogue: t-channel + bias + relu -> LDS h2, oc-major stride 129
            {
                float* s_h2 = (float*)s_pool;
                #pragma unroll
                for (int ri = 0; ri < 2; ri++) {
                    int lrow = rp*2 + ri;
                    int r_out = rg*4 + lrow;
                    int rcase = (r_out == 0) ? 1 : ((r_out == 31) ? 2 : 0);
                    #pragma unroll
                    for (int ch = 0; ch < 2; ch++) {
                        #pragma unroll
                        for (int reg = 0; reg < 4; reg++) {
                            int c = ch*16 + q*4 + reg;
                            int ccase = (c == 0) ? 1 : ((c == 31) ? 2 : 0);
                            const float* tsp = s_tsum + (rcase*3 + ccase)*64;
                            int pxl = lrow*32 + c;
                            #pragma unroll
                            for (int nn = 0; nn < 2; nn++) {
                                int oc = (np*2 + nn)*16 + l15;
                                s_h2[oc*129 + pxl] =
                                    fmaxf(acc2[ri][ch][nn][reg] + ts*tsp[oc] + s_b2v[oc], 0.0f);
                            }
                        }
                    }
                }
            }
            __syncthreads();

            // 5) conv3 (1x1 65->8) + mode epilogues (scope per row class)
            if (tid < 128) {
                const float* s_h2 = (const float*)s_pool;
                float a3[8];
                #pragma unroll
                for (int o = 0; o < 8; o++) a3[o] = fmaf(ts, s_w30[o], s_b3v[o]);
                #pragma unroll 8
                for (int c = 0; c < 64; c++) {
                    float xv = s_h2[c*129 + tid];
                    const float4* w4 = (const float4*)&s_w3t[c][0];
                    float4 wA = w4[0], wB = w4[1];
                    a3[0] = fmaf(wA.x, xv, a3[0]);
                    a3[1] = fmaf(wA.y, xv, a3[1]);
                    a3[2] = fmaf(wA.z, xv, a3[2]);
                    a3[3] = fmaf(wA.w, xv, a3[3]);
                    a3[4] = fmaf(wB.x, xv, a3[4]);
                    a3[5] = fmaf(wB.y, xv, a3[5]);
                    a3[6] = fmaf(wB.z, xv, a3[6]);
                    a3[7] = fmaf(wB.w, xv, a3[7]);
                }
                int lrow = tid >> 5;
                bool sysrow = (lrow == 0) | (lrow == 3);
                int px = rg*128 + tid;
                size_t pb8 = ((size_t)(b << 10) + px) << 3;
                st8(kout + pb8, a3, sysrow);
                if (mode == 1) {
                    float kv1[8], kv3[8], kv4[8], kv5[8], yv[8], r8[8];
                    ld8(ka + pb8, kv1, sysrow);
                    ld8(kb + 2*(size_t)NS + pb8, kv3, sysrow);
                    ld8(kb + 3*(size_t)NS + pb8, kv4, sysrow);
                    ld8(kb + 4*(size_t)NS + pb8, kv5, sysrow);
                    ld8(ya + pb8, yv, sysrow);
                    #pragma unroll
                    for (int c = 0; c < 8; c++)
                        r8[c] = yv[c] + dtc*(B1c*kv1[c] + B3c*kv3[c] + B4c*kv4[c]
                                             + B5c*kv5[c] + B6c*a3[c]);
                    st8(yb + pb8, r8, sysrow);
                } else if (mode == 2) {
                    float kv1[8], kv3[8], kv4[8], kv5[8], kv6[8], yv[8], y5v[8];
                    ld8(ka + pb8, kv1, sysrow);
                    ld8(kb + 2*(size_t)NS + pb8, kv3, sysrow);
                    ld8(kb + 3*(size_t)NS + pb8, kv4, sysrow);
                    ld8(kb + 4*(size_t)NS + pb8, kv5, sysrow);
                    ld8(kb + 5*(size_t)NS + pb8, kv6, sysrow);
                    ld8(ya + pb8, yv, sysrow);
                    ld8(yb + pb8, y5v, sysrow);
                    float ls = 0.0f;
                    #pragma unroll
                    for (int c = 0; c < 8; c++) {
                        float e = dtc*(E1c*kv1[c] + E3c*kv3[c] + E4c*kv4[c]
                                       + E5c*kv5[c] + E6c*kv6[c] + E7c*a3[c]);
                        float tol = ATOL + RTOL*fmaxf(fabsf(yv[c]), fabsf(y5v[c]));
                        float rr = e / tol;
                        ls += rr*rr;
                    }
                    s_red[tid] = ls;
                }
            }
            if (mode == 2) {
                if (tid >= 128) s_red[tid] = 0.0f;
                __syncthreads();
                for (int sft = 128; sft > 0; sft >>= 1) {
                    if (tid < sft) s_red[tid] += s_red[tid + sft];
                    __syncthreads();
                }
                if (tid == 0) st_sysf(&partp[tile], s_red[0]);
            }
            // release: __syncthreads drains vmcnt (sys stores at L3), then flag
            __syncthreads();
            if (tid == 0)
                __hip_atomic_store(&flags[tile], gev, __ATOMIC_RELAXED,
                                   __HIP_MEMORY_SCOPE_SYSTEM);
        }
    };

    int gev = 1;
    eval(ya, 0, g_cf[5], 0.0f, ka, 0, gev, part);   // k1 = f(t0, y0)
    gev++;

    for (int st = 0; st < 24; st++) {
        if (t >= 1.0f - 1e-7f) break;
        float* partp = part + (size_t)(st & 1)*512;
        for (int e = 0; e < 6; e++) {
            int nc = (e < 5) ? e + 1 : 0;
            const float* src = (e == 5) ? yb : ya;
            float* kout = (e < 5) ? kb + (size_t)(e + 1)*NS : kg;
            int mode = (e == 4) ? 1 : ((e == 5) ? 2 : 0);
            eval(src, nc, g_cf[e], g_ct[e], kout, mode, gev, partp);
            gev++;
        }
        rendezvous();   // all partials (sys) visible
        float v = ld_sysf(&partp[tid]) + ld_sysf(&partp[tid + 256]);
        s_red[tid] = v;
        __syncthreads();
        for (int sft = 128; sft > 0; sft >>= 1) {
            if (tid < sft) s_red[tid] += s_red[tid + sft];
            __syncthreads();
        }
        float red0 = s_red[0];
        __syncthreads();
        float err_norm = sqrtf(red0 / (float)NS);
        float dtc = fminf(dt, 1.0f - t);
        bool adv = (err_norm <= 1.0f);
        if (adv) {
            t = t + dtc;
            float* tmp = ya; ya = yb; yb = tmp;   // y <- y5
            tmp = ka; ka = kg; kg = tmp;          // k1 <- k7 (FSAL)
        }
        float safe = fmaxf(err_norm, 1e-10f);
        float factor = fminf(fmaxf(0.9f*powf(safe, -0.2f), 0.2f), 10.0f);
        dt = dtc*factor;
    }

    // flush private interior rows of final y to L3, then rendezvous
    for (int tile = blockIdx.x; tile < 512; tile += nblk) {
        int b = tile >> 3, rg = tile & 7;
        if (tid < 128) {
            int lrow = tid >> 5;
            if (lrow == 1 || lrow == 2) {
                int px = rg*128 + tid;
                float* yp = ya + (((size_t)(b << 10) + px) << 3);
                float4 v0 = *(const float4*)yp;
                float4 v1 = *(const float4*)(yp + 4);
                st_sysf2(yp,     v0.x, v0.y);
                st_sysf2(yp + 2, v0.z, v0.w);
                st_sysf2(yp + 4, v1.x, v1.y);
                st_sysf2(yp + 6, v1.z, v1.w);
            }
        }
    }
    rendezvous();

    // final linear head: y is px-major [b][px][8]; wl flat index = c*1024+px
    for (int bh = blockIdx.x; bh < 64; bh += nblk) {
        float* s_hred = (float*)s_pool;   // 10*256 floats overlay
        float acc[10];
        #pragma unroll
        for (int m = 0; m < 10; m++) acc[m] = 0.0f;
        for (int px = tid; px < 1024; px += 256) {
            const float* yp = ya + (((size_t)(bh << 10) + px) << 3);
            float yv[8];
            #pragma unroll
            for (int h = 0; h < 4; h++) {
                float2 v = ld_sysf2(yp + 2*h);
                yv[2*h] = v.x; yv[2*h+1] = v.y;
            }
            #pragma unroll
            for (int c = 0; c < 8; c++) {
                float v = yv[c];
                #pragma unroll
                for (int m = 0; m < 10; m++)
                    acc[m] = fmaf(v, wl[(size_t)m*8192 + (c << 10) + px], acc[m]);
            }
        }
        #pragma unroll
        for (int m = 0; m < 10; m++) s_hred[m*256 + tid] = acc[m];
        __syncthreads();
        for (int sft = 128; sft > 0; sft >>= 1) {
            if (tid < sft) {
                #pragma unroll
                for (int m = 0; m < 10; m++)
                    s_hred[m*256 + tid] += s_hred[m*256 + tid + sft];
            }
            __syncthreads();
        }
        if (tid < 10) out[bh*10 + tid] = s_hred[tid*256] + bl[tid];
        __syncthreads();
    }
}

// ---------------- host ----------------
extern "C" void kernel_launch(void* const* d_in, const int* in_sizes, int n_in,
                              void* d_out, int out_size, void* d_ws, size_t ws_size,
                              hipStream_t stream)
{
    const float* x  = (const float*)d_in[0];
    const float* w1 = (const float*)d_in[1];
    const float* b1 = (const float*)d_in[2];
    const float* w2 = (const float*)d_in[3];
    const float* b2 = (const float*)d_in[4];
    const float* w3 = (const float*)d_in[5];
    const float* b3 = (const float*)d_in[6];
    const float* wl = (const float*)d_in[7];
    const float* bl = (const float*)d_in[8];
    float* out = (float*)d_out;

    float* F = (float*)d_ws;
    float* part = F + OFF_PART;
    int*   flags = (int*)(F + OFF_FLAG);
    unsigned* cnt = (unsigned*)(F + OFF_CNT);
    float* tsum = F + OFF_TSUM;
    unsigned short* w2p = (unsigned short*)(F + OFF_W2P);
    float* y    = F + OFF_Y;
    float* y5   = F + OFF_Y5;
    float* kbp  = F + OFF_K;

    k_init<<<NS/256, 256, 0, stream>>>(x, y, flags, cnt);
    k_prepack<<<288, 256, 0, stream>>>(w2, w2p, tsum);

    // co-resident grid (cooperative launch for the residency guarantee)
    int maxb = 0;
    if (hipOccupancyMaxActiveBlocksPerMultiprocessor(&maxb,
            reinterpret_cast<const void*>(k_ode), 256, 0) != hipSuccess || maxb < 1)
        maxb = 1;
    int cus = 256;
    {
        int dev = 0;
        hipGetDevice(&dev);
        hipDeviceProp_t prop;
        if (hipGetDeviceProperties(&prop, dev) == hipSuccess && prop.multiProcessorCount > 0)
            cus = prop.multiProcessorCount;
    }
    long cap = (long)maxb * (long)cus;
    int gridn = (int)((cap < 512) ? cap : 512);
    if (gridn < 16) gridn = 16;

    void* args[] = {
        (void*)&w1, (void*)&b1, (void*)&b2, (void*)&w3, (void*)&b3,
        (void*)&w2p, (void*)&tsum, (void*)&wl, (void*)&bl,
        (void*)&y, (void*)&y5, (void*)&kbp, (void*)&part,
        (void*)&flags, (void*)&cnt, (void*)&out
    };
    hipLaunchCooperativeKernel((void*)k_ode, dim3(gridn), dim3(256), args, 0, stream);
}